// Round 1
// baseline (1509.524 us; speedup 1.0000x reference)
//
#include <hip/hip_runtime.h>
#include <math.h>

#define D_MODEL 768
#define NH 16
#define DH 48
#define NP 4
#define LQ 4096
#define BB 2
#define MTOT (BB * LQ)  // 8192

// ---------------------------------------------------------------------------
// GEMM: C = A(MxK) @ W(KxN) + bias  [row-major], optional fused final epilogue
// BM=128, BN=16*TN, KS=16. 256 threads, each computes 8 x TN outputs.
// MODE 0: C = acc + bias
// MODE 1: C = gamma[col] * (attn[row,col] + acc + bias)
// ---------------------------------------------------------------------------
template <int TN, int MODE>
__global__ __launch_bounds__(256) void gemm_kernel(
    const float* __restrict__ A, const float* __restrict__ W,
    const float* __restrict__ bias, float* __restrict__ C,
    int M, int N, int K,
    const float* __restrict__ attn, const float* __restrict__ gamma)
{
    constexpr int BM = 128;
    constexpr int BN = 16 * TN;
    constexpr int KS = 16;

    __shared__ float As[KS][BM];   // transposed: As[k][m]
    __shared__ float Bs[KS][BN];   // Bs[k][n]

    const int tid = threadIdx.x;
    const int tx = tid & 15;       // n direction
    const int ty = tid >> 4;       // m direction
    const int bm = blockIdx.y * BM;
    const int bn = blockIdx.x * BN;

    // A tile load mapping: 128 rows x 16 k. Each thread: 8 consecutive floats.
    const int arow = tid >> 1;            // 0..127
    const int acol = (tid & 1) * 8;       // 0 or 8
    // B tile load mapping: 16 k-rows x BN cols. Each thread: TN consecutive floats.
    const int brow = tid >> 4;            // 0..15
    const int bcol = (tid & 15) * TN;

    float acc[8][TN];
#pragma unroll
    for (int i = 0; i < 8; ++i)
#pragma unroll
        for (int j = 0; j < TN; ++j) acc[i][j] = 0.f;

    for (int kt = 0; kt < K; kt += KS) {
        // --- load A tile (transposed store) ---
        const float* ap = A + (size_t)(bm + arow) * K + kt + acol;
        float4 a0 = *(const float4*)(ap);
        float4 a1 = *(const float4*)(ap + 4);
        As[acol + 0][arow] = a0.x; As[acol + 1][arow] = a0.y;
        As[acol + 2][arow] = a0.z; As[acol + 3][arow] = a0.w;
        As[acol + 4][arow] = a1.x; As[acol + 5][arow] = a1.y;
        As[acol + 6][arow] = a1.z; As[acol + 7][arow] = a1.w;
        // --- load B tile ---
        const float* bp = W + (size_t)(kt + brow) * N + bn + bcol;
#pragma unroll
        for (int u = 0; u < TN / 4; ++u) {
            *(float4*)&Bs[brow][bcol + 4 * u] = *(const float4*)(bp + 4 * u);
        }
        __syncthreads();

#pragma unroll
        for (int kk = 0; kk < KS; ++kk) {
            float a[8], b[TN];
#pragma unroll
            for (int i = 0; i < 8; ++i) a[i] = As[kk][ty * 8 + i];
#pragma unroll
            for (int j = 0; j < TN; ++j) b[j] = Bs[kk][tx * TN + j];
#pragma unroll
            for (int i = 0; i < 8; ++i)
#pragma unroll
                for (int j = 0; j < TN; ++j) acc[i][j] = fmaf(a[i], b[j], acc[i][j]);
        }
        __syncthreads();
    }

#pragma unroll
    for (int i = 0; i < 8; ++i) {
        const size_t row = (size_t)(bm + ty * 8 + i);
#pragma unroll
        for (int j = 0; j < TN; ++j) {
            const int col = bn + tx * TN + j;
            float v = acc[i][j] + bias[col];
            if (MODE == 1) {
                v = (attn[row * N + col] + v) * gamma[col];
            }
            C[row * N + col] = v;
        }
    }
}

// ---------------------------------------------------------------------------
// Row LayerNorm over 768 cols. One block (256 thr) per row. In-place OK.
// ---------------------------------------------------------------------------
__global__ __launch_bounds__(256) void ln_kernel(
    const float* __restrict__ X, float* __restrict__ Y,
    const float* __restrict__ g, const float* __restrict__ beta)
{
    const int row = blockIdx.x;
    const float* x = X + (size_t)row * D_MODEL;
    const int t = threadIdx.x;
    float v0 = x[t], v1 = x[t + 256], v2 = x[t + 512];
    float s = v0 + v1 + v2;
    float s2 = v0 * v0 + v1 * v1 + v2 * v2;
#pragma unroll
    for (int m = 1; m < 64; m <<= 1) {
        s += __shfl_xor(s, m);
        s2 += __shfl_xor(s2, m);
    }
    __shared__ float red[8];
    const int wave = t >> 6, lane = t & 63;
    if (lane == 0) { red[wave] = s; red[wave + 4] = s2; }
    __syncthreads();
    s = red[0] + red[1] + red[2] + red[3];
    s2 = red[4] + red[5] + red[6] + red[7];
    const float mean = s * (1.f / 768.f);
    const float var = s2 * (1.f / 768.f) - mean * mean;
    const float rstd = rsqrtf(var + 1e-6f);
    float* y = Y + (size_t)row * D_MODEL;
    y[t]       = (v0 - mean) * rstd * g[t]       + beta[t];
    y[t + 256] = (v1 - mean) * rstd * g[t + 256] + beta[t + 256];
    y[t + 512] = (v2 - mean) * rstd * g[t + 512] + beta[t + 512];
}

// ---------------------------------------------------------------------------
// Offsets/attention-weights postprocess: softmax over P=4, compute sample locs.
// One thread per (b,q,h). off_raw: (M,128) [h*8+p*2+c]; aw_raw: (M,64) [h*4+p]
// loc out: (M*NH, P, 2); aw out: (M*NH, P)
// ---------------------------------------------------------------------------
__global__ __launch_bounds__(256) void offaw_post(
    const float* __restrict__ off_raw, const float* __restrict__ aw_raw,
    float* __restrict__ loc, float* __restrict__ aw)
{
    const int i = blockIdx.x * 256 + threadIdx.x;
    if (i >= MTOT * NH) return;
    const int h = i & (NH - 1);
    const int bq = i >> 4;
    const int q = bq & (LQ - 1);

    const float* orow = off_raw + (size_t)bq * 128 + h * 8;
    const float* arow = aw_raw + (size_t)bq * 64 + h * 4;

    float a0 = arow[0], a1 = arow[1], a2 = arow[2], a3 = arow[3];
    float mx = fmaxf(fmaxf(a0, a1), fmaxf(a2, a3));
    float e0 = expf(a0 - mx), e1 = expf(a1 - mx), e2 = expf(a2 - mx), e3 = expf(a3 - mx);
    float r = 1.f / (e0 + e1 + e2 + e3);

    const float refx = ((q & 63) + 0.5f) * (1.f / 64.f);
    const float refy = ((q >> 6) + 0.5f) * (1.f / 64.f);

#pragma unroll
    for (int p = 0; p < 4; ++p) {
        loc[(size_t)i * 8 + p * 2 + 0] = refx + orow[p * 2 + 0] * (1.f / 64.f);
        loc[(size_t)i * 8 + p * 2 + 1] = refy + orow[p * 2 + 1] * (1.f / 64.f);
    }
    aw[(size_t)i * 4 + 0] = e0 * r;
    aw[(size_t)i * 4 + 1] = e1 * r;
    aw[(size_t)i * 4 + 2] = e2 * r;
    aw[(size_t)i * 4 + 3] = e3 * r;
}

// ---------------------------------------------------------------------------
// Bilinear sampling + weighted sum over P points.
// One thread per (b,q,h,d). value: (B, 4096, NH, DH) = (B,4096,768) rows.
// out: (B, Lq, NH, DH) contiguous = (B,Lq,768)
// ---------------------------------------------------------------------------
__global__ __launch_bounds__(256) void sample_kernel(
    const float* __restrict__ value, const float* __restrict__ loc,
    const float* __restrict__ aw, float* __restrict__ out)
{
    const int idx = blockIdx.x * 256 + threadIdx.x;  // MTOT*768
    const int d = idx % DH;
    const int bqh = idx / DH;
    const int h = bqh & (NH - 1);
    const int bq = bqh >> 4;
    const int b = bq >> 12;  // /4096

    const float* lc = loc + (size_t)bqh * 8;
    const float* awp = aw + (size_t)bqh * 4;
    const float* vbase = value + (size_t)b * LQ * D_MODEL + h * DH + d;

    float acc = 0.f;
#pragma unroll
    for (int p = 0; p < 4; ++p) {
        const float x = lc[p * 2 + 0] * 64.f - 0.5f;
        const float y = lc[p * 2 + 1] * 64.f - 0.5f;
        const float xf = floorf(x), yf = floorf(y);
        const float wx1 = x - xf, wy1 = y - yf;
        const float wx0 = 1.f - wx1, wy0 = 1.f - wy1;
        const int x0 = (int)xf, y0 = (int)yf;
        const int x1 = x0 + 1, y1 = y0 + 1;
        const float wp = awp[p];
        const bool vx0 = (x0 >= 0) & (x0 < 64);
        const bool vx1 = (x1 >= 0) & (x1 < 64);
        const bool vy0 = (y0 >= 0) & (y0 < 64);
        const bool vy1 = (y1 >= 0) & (y1 < 64);
        if (vy0) {
            const float* rowp = vbase + (size_t)(y0 * 64) * D_MODEL;
            if (vx0) acc += wp * wx0 * wy0 * rowp[(size_t)x0 * D_MODEL];
            if (vx1) acc += wp * wx1 * wy0 * rowp[(size_t)x1 * D_MODEL];
        }
        if (vy1) {
            const float* rowp = vbase + (size_t)(y1 * 64) * D_MODEL;
            if (vx0) acc += wp * wx0 * wy1 * rowp[(size_t)x0 * D_MODEL];
            if (vx1) acc += wp * wx1 * wy1 * rowp[(size_t)x1 * D_MODEL];
        }
    }
    out[idx] = acc;
}

// ---------------------------------------------------------------------------
extern "C" void kernel_launch(void* const* d_in, const int* in_sizes, int n_in,
                              void* d_out, int out_size, void* d_ws, size_t ws_size,
                              hipStream_t stream)
{
    const float* query   = (const float*)d_in[0];
    const float* feat    = (const float*)d_in[1];
    // d_in[2] spatial_shapes, d_in[3] level_start_index: fixed 64x64, start 0
    const float* qn_W    = (const float*)d_in[4];
    const float* qn_b    = (const float*)d_in[5];
    const float* qn_g    = (const float*)d_in[6];
    const float* qn_beta = (const float*)d_in[7];
    const float* fn_W    = (const float*)d_in[8];
    const float* fn_b    = (const float*)d_in[9];
    const float* fn_g    = (const float*)d_in[10];
    const float* fn_beta = (const float*)d_in[11];
    const float* nm_g    = (const float*)d_in[12];
    const float* nm_beta = (const float*)d_in[13];
    const float* gamma1  = (const float*)d_in[14];
    const float* c_Wv    = (const float*)d_in[15];
    const float* c_bv    = (const float*)d_in[16];
    const float* c_Woff  = (const float*)d_in[17];
    const float* c_boff  = (const float*)d_in[18];
    const float* c_Wa    = (const float*)d_in[19];
    const float* c_ba    = (const float*)d_in[20];
    const float* c_Wo    = (const float*)d_in[21];
    const float* c_bo    = (const float*)d_in[22];
    const float* s_Wv    = (const float*)d_in[23];
    const float* s_bv    = (const float*)d_in[24];
    const float* s_Woff  = (const float*)d_in[25];
    const float* s_boff  = (const float*)d_in[26];
    const float* s_Wa    = (const float*)d_in[27];
    const float* s_ba    = (const float*)d_in[28];
    const float* s_Wo    = (const float*)d_in[29];
    const float* s_bo    = (const float*)d_in[30];

    float* ws = (float*)d_ws;
    const size_t SZ = (size_t)MTOT * D_MODEL;  // 6291456
    float* qn      = ws;            // also reused as attn1
    float* fn      = ws + SZ;
    float* val     = ws + 2 * SZ;
    float* samp    = ws + 3 * SZ;
    float* attn    = ws + 4 * SZ;
    float* off_raw = ws + 5 * SZ;                    // MTOT*128
    float* aw_raw  = off_raw + (size_t)MTOT * 128;   // MTOT*64
    float* loc     = aw_raw + (size_t)MTOT * 64;     // MTOT*NH*NP*2 = MTOT*128
    float* aws     = loc + (size_t)MTOT * 128;       // MTOT*NH*NP = MTOT*64

    float* out = (float*)d_out;

    const dim3 blk(256);
    const dim3 g_main(D_MODEL / 128, MTOT / 128);  // (6, 64)
    const dim3 g_off(2, MTOT / 128);               // N=128
    const dim3 g_aw(1, MTOT / 128);                // N=64
    const int ln_grid = MTOT;
    const int pp_grid = (MTOT * NH + 255) / 256;
    const int sm_grid = (int)(SZ / 256);

    // ---- cross attention ----
    gemm_kernel<8, 0><<<g_main, blk, 0, stream>>>(query, qn_W, qn_b, qn, MTOT, D_MODEL, D_MODEL, nullptr, nullptr);
    ln_kernel<<<ln_grid, blk, 0, stream>>>(qn, qn, qn_g, qn_beta);
    gemm_kernel<8, 0><<<g_main, blk, 0, stream>>>(feat, fn_W, fn_b, fn, MTOT, D_MODEL, D_MODEL, nullptr, nullptr);
    ln_kernel<<<ln_grid, blk, 0, stream>>>(fn, fn, fn_g, fn_beta);
    gemm_kernel<8, 0><<<g_main, blk, 0, stream>>>(fn, c_Wv, c_bv, val, MTOT, D_MODEL, D_MODEL, nullptr, nullptr);
    gemm_kernel<4, 0><<<g_off, blk, 0, stream>>>(qn, c_Woff, c_boff, off_raw, MTOT, 128, D_MODEL, nullptr, nullptr);
    gemm_kernel<4, 0><<<g_aw, blk, 0, stream>>>(qn, c_Wa, c_ba, aw_raw, MTOT, 64, D_MODEL, nullptr, nullptr);
    offaw_post<<<pp_grid, blk, 0, stream>>>(off_raw, aw_raw, loc, aws);
    sample_kernel<<<sm_grid, blk, 0, stream>>>(val, loc, aws, samp);
    gemm_kernel<8, 0><<<g_main, blk, 0, stream>>>(samp, c_Wo, c_bo, attn, MTOT, D_MODEL, D_MODEL, nullptr, nullptr);

    // ---- self attention ----
    ln_kernel<<<ln_grid, blk, 0, stream>>>(attn, qn, nm_g, nm_beta);  // attn1 -> qn buf
    gemm_kernel<8, 0><<<g_main, blk, 0, stream>>>(qn, s_Wv, s_bv, val, MTOT, D_MODEL, D_MODEL, nullptr, nullptr);
    gemm_kernel<4, 0><<<g_off, blk, 0, stream>>>(qn, s_Woff, s_boff, off_raw, MTOT, 128, D_MODEL, nullptr, nullptr);
    gemm_kernel<4, 0><<<g_aw, blk, 0, stream>>>(qn, s_Wa, s_ba, aw_raw, MTOT, 64, D_MODEL, nullptr, nullptr);
    offaw_post<<<pp_grid, blk, 0, stream>>>(off_raw, aw_raw, loc, aws);
    sample_kernel<<<sm_grid, blk, 0, stream>>>(val, loc, aws, samp);
    // final: out = gamma1 * (attn + samp @ s_Wo + s_bo)
    gemm_kernel<8, 1><<<g_main, blk, 0, stream>>>(samp, s_Wo, s_bo, out, MTOT, D_MODEL, D_MODEL, attn, gamma1);
}

// Round 2
// 999.832 us; speedup vs baseline: 1.5098x; 1.5098x over previous
//
#include <hip/hip_runtime.h>
#include <hip/hip_bf16.h>
#include <math.h>

#define D_MODEL 768
#define NH 16
#define DH 48
#define NP 4
#define LQ 4096
#define BB 2
#define MTOT (BB * LQ)  // 8192

typedef __attribute__((ext_vector_type(8))) short short8_t;
typedef __attribute__((ext_vector_type(4))) float floatx4;

__device__ __forceinline__ void load_lds16(const void* g, void* l) {
    __builtin_amdgcn_global_load_lds((const __attribute__((address_space(1))) void*)g,
                                     (__attribute__((address_space(3))) void*)l, 16, 0, 0);
}

__device__ __forceinline__ void f32_to_bf16_pair(float x, __hip_bfloat16& hi, __hip_bfloat16& lo) {
    hi = __float2bfloat16(x);
    lo = __float2bfloat16(x - __bfloat162float(hi));
}

// ---------------------------------------------------------------------------
// Split-bf16 MFMA GEMM. C(M x 768) = A2(M x 1536 bf16 [Ah|Al]) @ W2t(768 x 2304 bf16)
// logical K = 2304: phase0 Ah*Wh, phase1 Al*Wh, phase2 Ah*Wl.
// 128x128 tile, BK=32, 4 waves (2x2), each wave 64x64 via 4x4 16x16x32 MFMA.
// MODE 0: C = acc + bias ; MODE 1: C = gamma[col]*(attn[row,col] + acc + bias)
// ---------------------------------------------------------------------------
template <int MODE>
__global__ __launch_bounds__(256) void gemm_mfma(
    const short* __restrict__ A2, const short* __restrict__ Wt,
    const float* __restrict__ bias, float* __restrict__ C,
    const float* __restrict__ attn, const float* __restrict__ gamma)
{
    constexpr int KA = 1536, KW = 2304, N = 768;
    __shared__ short As[128 * 32];
    __shared__ short Bs[128 * 32];

    // XCD-aware swizzle: 384 blocks, 384/8 = 48 per XCD (bijective)
    const int bid = blockIdx.x;
    const int swz = (bid & 7) * 48 + (bid >> 3);
    const int tm = swz & 63;   // 64 row tiles (fastest -> shares B strip)
    const int tn = swz >> 6;   // 6 col tiles
    const int bm = tm * 128, bn = tn * 128;

    const int t = threadIdx.x;
    const int lane = t & 63;
    const int w = t >> 6;
    const int wm = (w >> 1) * 64, wn = (w & 1) * 64;

    floatx4 acc[4][4] = {};

    // staging mapping: thread t -> row t>>2, 16B chunk t&3 (issue 0: rows 0..63)
    const int r0 = t >> 2;
    const int c8 = (t & 3) * 8;
    short* AsW0 = &As[w * 512];          // wave-uniform LDS bases (bytes w*1024)
    short* AsW1 = &As[2048 + w * 512];
    short* BsW0 = &Bs[w * 512];
    short* BsW1 = &Bs[2048 + w * 512];

    const int lrow = lane & 15;
    const int lk = (lane >> 4) * 8;

    for (int kt = 0; kt < KW; kt += 32) {
        const int ak = (kt < 1536 ? kt : kt - 1536) + c8;
        load_lds16(A2 + (size_t)(bm + r0) * KA + ak, AsW0);
        load_lds16(A2 + (size_t)(bm + 64 + r0) * KA + ak, AsW1);
        load_lds16(Wt + (size_t)(bn + r0) * KW + kt + c8, BsW0);
        load_lds16(Wt + (size_t)(bn + 64 + r0) * KW + kt + c8, BsW1);
        __syncthreads();  // drains vmcnt before LDS reads

        short8_t af[4], bf[4];
#pragma unroll
        for (int i = 0; i < 4; ++i) {
            af[i] = *(const short8_t*)&As[(wm + i * 16 + lrow) * 32 + lk];
            bf[i] = *(const short8_t*)&Bs[(wn + i * 16 + lrow) * 32 + lk];
        }
#pragma unroll
        for (int i = 0; i < 4; ++i)
#pragma unroll
            for (int j = 0; j < 4; ++j)
                acc[i][j] = __builtin_amdgcn_mfma_f32_16x16x32_bf16(af[i], bf[j], acc[i][j], 0, 0, 0);
        __syncthreads();
    }

    // epilogue: C/D layout col=lane&15, row=(lane>>4)*4+reg
    const int rquad = (lane >> 4) * 4;
#pragma unroll
    for (int i = 0; i < 4; ++i) {
#pragma unroll
        for (int j = 0; j < 4; ++j) {
            const int col = bn + wn + j * 16 + lrow;
            const float bcol = bias[col];
#pragma unroll
            for (int r = 0; r < 4; ++r) {
                const size_t row = (size_t)(bm + wm + i * 16 + rquad + r);
                float v = acc[i][j][r] + bcol;
                if (MODE == 1) v = (attn[row * N + col] + v) * gamma[col];
                C[row * N + col] = v;
            }
        }
    }
}

// ---------------------------------------------------------------------------
// fp32 VALU GEMM for skinny N (128 / 64). BM=128, BN=16*TN, KS=16.
// ---------------------------------------------------------------------------
template <int TN>
__global__ __launch_bounds__(256) void gemm_skinny(
    const float* __restrict__ A, const float* __restrict__ W,
    const float* __restrict__ bias, float* __restrict__ C,
    int M, int N, int K)
{
    constexpr int BM = 128;
    constexpr int BN = 16 * TN;
    constexpr int KS = 16;
    __shared__ float As[KS][BM];
    __shared__ float Bs[KS][BN];

    const int tid = threadIdx.x;
    const int tx = tid & 15;
    const int ty = tid >> 4;
    const int bm = blockIdx.y * BM;
    const int bn = blockIdx.x * BN;
    const int arow = tid >> 1;
    const int acol = (tid & 1) * 8;
    const int brow = tid >> 4;
    const int bcol = (tid & 15) * TN;

    float acc[8][TN];
#pragma unroll
    for (int i = 0; i < 8; ++i)
#pragma unroll
        for (int j = 0; j < TN; ++j) acc[i][j] = 0.f;

    for (int kt = 0; kt < K; kt += KS) {
        const float* ap = A + (size_t)(bm + arow) * K + kt + acol;
        float4 a0 = *(const float4*)(ap);
        float4 a1 = *(const float4*)(ap + 4);
        As[acol + 0][arow] = a0.x; As[acol + 1][arow] = a0.y;
        As[acol + 2][arow] = a0.z; As[acol + 3][arow] = a0.w;
        As[acol + 4][arow] = a1.x; As[acol + 5][arow] = a1.y;
        As[acol + 6][arow] = a1.z; As[acol + 7][arow] = a1.w;
        const float* bp = W + (size_t)(kt + brow) * N + bn + bcol;
#pragma unroll
        for (int u = 0; u < TN / 4; ++u)
            *(float4*)&Bs[brow][bcol + 4 * u] = *(const float4*)(bp + 4 * u);
        __syncthreads();
#pragma unroll
        for (int kk = 0; kk < KS; ++kk) {
            float a[8], b[TN];
#pragma unroll
            for (int i = 0; i < 8; ++i) a[i] = As[kk][ty * 8 + i];
#pragma unroll
            for (int j = 0; j < TN; ++j) b[j] = Bs[kk][tx * TN + j];
#pragma unroll
            for (int i = 0; i < 8; ++i)
#pragma unroll
                for (int j = 0; j < TN; ++j) acc[i][j] = fmaf(a[i], b[j], acc[i][j]);
        }
        __syncthreads();
    }
#pragma unroll
    for (int i = 0; i < 8; ++i) {
        const size_t row = (size_t)(bm + ty * 8 + i);
#pragma unroll
        for (int j = 0; j < TN; ++j) {
            const int col = bn + tx * TN + j;
            C[row * N + col] = acc[i][j] + bias[col];
        }
    }
}

// ---------------------------------------------------------------------------
// LayerNorm over 768 cols, optional fused fp32 -> split-bf16 conversion.
// ---------------------------------------------------------------------------
__global__ __launch_bounds__(256) void ln_kernel(
    const float* __restrict__ X, float* __restrict__ Y,
    __hip_bfloat16* __restrict__ A2,  // nullptr or [M][1536] hi|lo
    const float* __restrict__ g, const float* __restrict__ beta)
{
    const int row = blockIdx.x;
    const float* x = X + (size_t)row * D_MODEL;
    const int t = threadIdx.x;
    float v0 = x[t], v1 = x[t + 256], v2 = x[t + 512];
    float s = v0 + v1 + v2;
    float s2 = v0 * v0 + v1 * v1 + v2 * v2;
#pragma unroll
    for (int m = 1; m < 64; m <<= 1) {
        s += __shfl_xor(s, m);
        s2 += __shfl_xor(s2, m);
    }
    __shared__ float red[8];
    const int wave = t >> 6, lane = t & 63;
    if (lane == 0) { red[wave] = s; red[wave + 4] = s2; }
    __syncthreads();
    s = red[0] + red[1] + red[2] + red[3];
    s2 = red[4] + red[5] + red[6] + red[7];
    const float mean = s * (1.f / 768.f);
    const float var = s2 * (1.f / 768.f) - mean * mean;
    const float rstd = rsqrtf(var + 1e-6f);
    float* y = Y + (size_t)row * D_MODEL;
    float y0 = (v0 - mean) * rstd * g[t] + beta[t];
    float y1 = (v1 - mean) * rstd * g[t + 256] + beta[t + 256];
    float y2 = (v2 - mean) * rstd * g[t + 512] + beta[t + 512];
    y[t] = y0; y[t + 256] = y1; y[t + 512] = y2;
    if (A2) {
        __hip_bfloat16* arow = A2 + (size_t)row * 1536;
        __hip_bfloat16 h, l;
        f32_to_bf16_pair(y0, h, l); arow[t] = h;       arow[t + 768] = l;
        f32_to_bf16_pair(y1, h, l); arow[t + 256] = h; arow[t + 1024] = l;
        f32_to_bf16_pair(y2, h, l); arow[t + 512] = h; arow[t + 1280] = l;
    }
}

// ---------------------------------------------------------------------------
// fp32 (M x 768) -> split-bf16 A2 (M x 1536 = [hi | lo])
// ---------------------------------------------------------------------------
__global__ __launch_bounds__(256) void convert_act(
    const float* __restrict__ X, __hip_bfloat16* __restrict__ A2)
{
    const int i = blockIdx.x * 256 + threadIdx.x;  // over MTOT*192 float4s
    if (i >= MTOT * 192) return;
    const int row = i / 192;
    const int c4 = (i - row * 192) * 4;
    const float4 v = *(const float4*)(X + (size_t)row * 768 + c4);
    __hip_bfloat16* arow = A2 + (size_t)row * 1536;
    __hip_bfloat16 h, l;
    f32_to_bf16_pair(v.x, h, l); arow[c4 + 0] = h; arow[768 + c4 + 0] = l;
    f32_to_bf16_pair(v.y, h, l); arow[c4 + 1] = h; arow[768 + c4 + 1] = l;
    f32_to_bf16_pair(v.z, h, l); arow[c4 + 2] = h; arow[768 + c4 + 2] = l;
    f32_to_bf16_pair(v.w, h, l); arow[c4 + 3] = h; arow[768 + c4 + 3] = l;
}

// ---------------------------------------------------------------------------
// Convert 6 weights W(768x768 fp32) -> W2t(768x2304 bf16) = [Wh;Wh;Wl] transposed,
// LDS-tiled transpose. grid.x = 576 (24x24 tiles of 32x32), grid.y = weight idx.
// ---------------------------------------------------------------------------
__global__ __launch_bounds__(256) void convert_w6(
    const float* __restrict__ w0, const float* __restrict__ w1,
    const float* __restrict__ w2, const float* __restrict__ w3,
    const float* __restrict__ w4, const float* __restrict__ w5,
    __hip_bfloat16* __restrict__ Wall)
{
    const int wi = blockIdx.y;
    const float* W = (wi == 0) ? w0 : (wi == 1) ? w1 : (wi == 2) ? w2
                   : (wi == 3) ? w3 : (wi == 4) ? w4 : w5;
    __hip_bfloat16* Wt = Wall + (size_t)wi * 768 * 2304;

    __shared__ float tile[32][33];
    const int tk0 = (blockIdx.x / 24) * 32;
    const int tn0 = (blockIdx.x % 24) * 32;
    const int t = threadIdx.x;
#pragma unroll
    for (int r = 0; r < 4; ++r) {
        const int row = r * 8 + (t >> 5);
        const int col = t & 31;
        tile[row][col] = W[(size_t)(tk0 + row) * 768 + tn0 + col];
    }
    __syncthreads();
    const int n = t >> 3;            // 0..31
    const int kq = (t & 7) * 4;      // 0..28
    __hip_bfloat16* dst = Wt + (size_t)(tn0 + n) * 2304 + tk0 + kq;
#pragma unroll
    for (int u = 0; u < 4; ++u) {
        __hip_bfloat16 h, l;
        f32_to_bf16_pair(tile[kq + u][n], h, l);
        dst[u] = h;
        dst[768 + u] = h;
        dst[1536 + u] = l;
    }
}

// ---------------------------------------------------------------------------
// softmax over P=4 + sampling loc computation
// ---------------------------------------------------------------------------
__global__ __launch_bounds__(256) void offaw_post(
    const float* __restrict__ off_raw, const float* __restrict__ aw_raw,
    float* __restrict__ loc, float* __restrict__ aw)
{
    const int i = blockIdx.x * 256 + threadIdx.x;
    if (i >= MTOT * NH) return;
    const int h = i & (NH - 1);
    const int bq = i >> 4;
    const int q = bq & (LQ - 1);

    const float* orow = off_raw + (size_t)bq * 128 + h * 8;
    const float* arow = aw_raw + (size_t)bq * 64 + h * 4;

    float a0 = arow[0], a1 = arow[1], a2 = arow[2], a3 = arow[3];
    float mx = fmaxf(fmaxf(a0, a1), fmaxf(a2, a3));
    float e0 = expf(a0 - mx), e1 = expf(a1 - mx), e2 = expf(a2 - mx), e3 = expf(a3 - mx);
    float r = 1.f / (e0 + e1 + e2 + e3);

    const float refx = ((q & 63) + 0.5f) * (1.f / 64.f);
    const float refy = ((q >> 6) + 0.5f) * (1.f / 64.f);
#pragma unroll
    for (int p = 0; p < 4; ++p) {
        loc[(size_t)i * 8 + p * 2 + 0] = refx + orow[p * 2 + 0] * (1.f / 64.f);
        loc[(size_t)i * 8 + p * 2 + 1] = refy + orow[p * 2 + 1] * (1.f / 64.f);
    }
    aw[(size_t)i * 4 + 0] = e0 * r;
    aw[(size_t)i * 4 + 1] = e1 * r;
    aw[(size_t)i * 4 + 2] = e2 * r;
    aw[(size_t)i * 4 + 3] = e3 * r;
}

// ---------------------------------------------------------------------------
// Bilinear sampling + weighted sum over P points.
// ---------------------------------------------------------------------------
__global__ __launch_bounds__(256) void sample_kernel(
    const float* __restrict__ value, const float* __restrict__ loc,
    const float* __restrict__ aw, float* __restrict__ out)
{
    const int idx = blockIdx.x * 256 + threadIdx.x;
    const int d = idx % DH;
    const int bqh = idx / DH;
    const int h = bqh & (NH - 1);
    const int bq = bqh >> 4;
    const int b = bq >> 12;

    const float* lc = loc + (size_t)bqh * 8;
    const float* awp = aw + (size_t)bqh * 4;
    const float* vbase = value + (size_t)b * LQ * D_MODEL + h * DH + d;

    float acc = 0.f;
#pragma unroll
    for (int p = 0; p < 4; ++p) {
        const float x = lc[p * 2 + 0] * 64.f - 0.5f;
        const float y = lc[p * 2 + 1] * 64.f - 0.5f;
        const float xf = floorf(x), yf = floorf(y);
        const float wx1 = x - xf, wy1 = y - yf;
        const float wx0 = 1.f - wx1, wy0 = 1.f - wy1;
        const int x0 = (int)xf, y0 = (int)yf;
        const int x1 = x0 + 1, y1 = y0 + 1;
        const float wp = awp[p];
        const bool vx0 = (x0 >= 0) & (x0 < 64);
        const bool vx1 = (x1 >= 0) & (x1 < 64);
        const bool vy0 = (y0 >= 0) & (y0 < 64);
        const bool vy1 = (y1 >= 0) & (y1 < 64);
        if (vy0) {
            const float* rowp = vbase + (size_t)(y0 * 64) * D_MODEL;
            if (vx0) acc += wp * wx0 * wy0 * rowp[(size_t)x0 * D_MODEL];
            if (vx1) acc += wp * wx1 * wy0 * rowp[(size_t)x1 * D_MODEL];
        }
        if (vy1) {
            const float* rowp = vbase + (size_t)(y1 * 64) * D_MODEL;
            if (vx0) acc += wp * wx0 * wy1 * rowp[(size_t)x0 * D_MODEL];
            if (vx1) acc += wp * wx1 * wy1 * rowp[(size_t)x1 * D_MODEL];
        }
    }
    out[idx] = acc;
}

// ---------------------------------------------------------------------------
extern "C" void kernel_launch(void* const* d_in, const int* in_sizes, int n_in,
                              void* d_out, int out_size, void* d_ws, size_t ws_size,
                              hipStream_t stream)
{
    const float* query   = (const float*)d_in[0];
    const float* feat    = (const float*)d_in[1];
    const float* qn_W    = (const float*)d_in[4];
    const float* qn_b    = (const float*)d_in[5];
    const float* qn_g    = (const float*)d_in[6];
    const float* qn_beta = (const float*)d_in[7];
    const float* fn_W    = (const float*)d_in[8];
    const float* fn_b    = (const float*)d_in[9];
    const float* fn_g    = (const float*)d_in[10];
    const float* fn_beta = (const float*)d_in[11];
    const float* nm_g    = (const float*)d_in[12];
    const float* nm_beta = (const float*)d_in[13];
    const float* gamma1  = (const float*)d_in[14];
    const float* c_Wv    = (const float*)d_in[15];
    const float* c_bv    = (const float*)d_in[16];
    const float* c_Woff  = (const float*)d_in[17];
    const float* c_boff  = (const float*)d_in[18];
    const float* c_Wa    = (const float*)d_in[19];
    const float* c_ba    = (const float*)d_in[20];
    const float* c_Wo    = (const float*)d_in[21];
    const float* c_bo    = (const float*)d_in[22];
    const float* s_Wv    = (const float*)d_in[23];
    const float* s_bv    = (const float*)d_in[24];
    const float* s_Woff  = (const float*)d_in[25];
    const float* s_boff  = (const float*)d_in[26];
    const float* s_Wa    = (const float*)d_in[27];
    const float* s_ba    = (const float*)d_in[28];
    const float* s_Wo    = (const float*)d_in[29];
    const float* s_bo    = (const float*)d_in[30];

    float* ws = (float*)d_ws;
    const size_t SZ = (size_t)MTOT * D_MODEL;  // 6291456
    float* buf0    = ws;                 // qn / attn1
    float* buf1    = ws + SZ;            // fn / samp
    float* buf2    = ws + 2 * SZ;        // val
    float* buf3    = ws + 3 * SZ;        // attn
    float* off_raw = ws + 4 * SZ;                    // MTOT*128
    float* aw_raw  = off_raw + (size_t)MTOT * 128;   // MTOT*64
    float* loc     = aw_raw + (size_t)MTOT * 64;     // MTOT*128
    float* aws     = loc + (size_t)MTOT * 128;       // MTOT*64
    __hip_bfloat16* A2   = (__hip_bfloat16*)(aws + (size_t)MTOT * 64);  // M x 1536
    __hip_bfloat16* Wall = A2 + (size_t)MTOT * 1536;                    // 6 x 768 x 2304
    // weight slots: 0=qn_W 1=fn_W 2=c_Wv 3=c_Wo 4=s_Wv 5=s_Wo
    __hip_bfloat16* W_qn  = Wall + (size_t)0 * 768 * 2304;
    __hip_bfloat16* W_fn  = Wall + (size_t)1 * 768 * 2304;
    __hip_bfloat16* W_cWv = Wall + (size_t)2 * 768 * 2304;
    __hip_bfloat16* W_cWo = Wall + (size_t)3 * 768 * 2304;
    __hip_bfloat16* W_sWv = Wall + (size_t)4 * 768 * 2304;
    __hip_bfloat16* W_sWo = Wall + (size_t)5 * 768 * 2304;

    float* out = (float*)d_out;

    const dim3 blk(256);
    const dim3 g_mfma(384);                 // 64 x 6 tiles
    const dim3 g_off(2, MTOT / 128);
    const dim3 g_aw(1, MTOT / 128);
    const dim3 g_wc(576, 6);
    const int ln_grid = MTOT;
    const int ca_grid = (MTOT * 192 + 255) / 256;
    const int pp_grid = (MTOT * NH + 255) / 256;
    const int sm_grid = (int)(SZ / 256);

    // weights -> split-bf16 transposed (once per call)
    convert_w6<<<g_wc, blk, 0, stream>>>(qn_W, fn_W, c_Wv, c_Wo, s_Wv, s_Wo, Wall);

    // ---- cross attention ----
    convert_act<<<ca_grid, blk, 0, stream>>>(query, A2);
    gemm_mfma<0><<<g_mfma, blk, 0, stream>>>((const short*)A2, (const short*)W_qn, qn_b, buf0, nullptr, nullptr);
    ln_kernel<<<ln_grid, blk, 0, stream>>>(buf0, buf0, nullptr, qn_g, qn_beta);
    convert_act<<<ca_grid, blk, 0, stream>>>(feat, A2);
    gemm_mfma<0><<<g_mfma, blk, 0, stream>>>((const short*)A2, (const short*)W_fn, fn_b, buf1, nullptr, nullptr);
    ln_kernel<<<ln_grid, blk, 0, stream>>>(buf1, buf1, A2, fn_g, fn_beta);
    gemm_mfma<0><<<g_mfma, blk, 0, stream>>>((const short*)A2, (const short*)W_cWv, c_bv, buf2, nullptr, nullptr);
    gemm_skinny<4><<<g_off, blk, 0, stream>>>(buf0, c_Woff, c_boff, off_raw, MTOT, 128, D_MODEL);
    gemm_skinny<4><<<g_aw, blk, 0, stream>>>(buf0, c_Wa, c_ba, aw_raw, MTOT, 64, D_MODEL);
    offaw_post<<<pp_grid, blk, 0, stream>>>(off_raw, aw_raw, loc, aws);
    sample_kernel<<<sm_grid, blk, 0, stream>>>(buf2, loc, aws, buf1);
    convert_act<<<ca_grid, blk, 0, stream>>>(buf1, A2);
    gemm_mfma<0><<<g_mfma, blk, 0, stream>>>((const short*)A2, (const short*)W_cWo, c_bo, buf3, nullptr, nullptr);

    // ---- self attention ----
    ln_kernel<<<ln_grid, blk, 0, stream>>>(buf3, buf0, A2, nm_g, nm_beta);
    gemm_mfma<0><<<g_mfma, blk, 0, stream>>>((const short*)A2, (const short*)W_sWv, s_bv, buf2, nullptr, nullptr);
    gemm_skinny<4><<<g_off, blk, 0, stream>>>(buf0, s_Woff, s_boff, off_raw, MTOT, 128, D_MODEL);
    gemm_skinny<4><<<g_aw, blk, 0, stream>>>(buf0, s_Wa, s_ba, aw_raw, MTOT, 64, D_MODEL);
    offaw_post<<<pp_grid, blk, 0, stream>>>(off_raw, aw_raw, loc, aws);
    sample_kernel<<<sm_grid, blk, 0, stream>>>(buf2, loc, aws, buf1);
    convert_act<<<ca_grid, blk, 0, stream>>>(buf1, A2);
    gemm_mfma<1><<<g_mfma, blk, 0, stream>>>((const short*)A2, (const short*)W_sWo, s_bo, out, buf3, gamma1);
}

// Round 4
// 577.510 us; speedup vs baseline: 2.6138x; 1.7313x over previous
//
#include <hip/hip_runtime.h>
#include <hip/hip_bf16.h>
#include <math.h>

#define D_MODEL 768
#define NH 16
#define DH 48
#define NP 4
#define LQ 4096
#define BB 2
#define MTOT (BB * LQ)  // 8192

typedef __attribute__((ext_vector_type(8))) short short8_t;
typedef __attribute__((ext_vector_type(4))) float floatx4;

__device__ __forceinline__ void load_lds16(const void* g, void* l) {
    __builtin_amdgcn_global_load_lds((const __attribute__((address_space(1))) void*)g,
                                     (__attribute__((address_space(3))) void*)l, 16, 0, 0);
}

__device__ __forceinline__ void f32_to_bf16_pair(float x, __hip_bfloat16& hi, __hip_bfloat16& lo) {
    hi = __float2bfloat16(x);
    lo = __float2bfloat16(x - __bfloat162float(hi));
}

// ---------------------------------------------------------------------------
// Shared MFMA GEMM tile body. A2: (M x 1536 bf16 [Ah|Al]); Wt: (ldc-cols x 2304).
// 128x128 tile at (tm, tn), BK=32, 4 waves (2x2), 4x4 16x16x32 MFMA per wave.
// ---------------------------------------------------------------------------
template <int MODE>
__device__ __forceinline__ void gemm_body(
    const short* __restrict__ A2, const short* __restrict__ Wt,
    const float* __restrict__ bias, float* __restrict__ C, int ldc,
    int tm, int tn,
    const float* __restrict__ attn, const float* __restrict__ gamma)
{
    constexpr int KA = 1536, KW = 2304;
    __shared__ short As[128 * 32];
    __shared__ short Bs[128 * 32];

    const int bm = tm * 128, bn = tn * 128;
    const int t = threadIdx.x;
    const int lane = t & 63;
    const int w = t >> 6;
    const int wm = (w >> 1) * 64, wn = (w & 1) * 64;

    floatx4 acc[4][4] = {};

    const int r0 = t >> 2;
    const int c8 = (t & 3) * 8;
    short* AsW0 = &As[w * 512];
    short* AsW1 = &As[2048 + w * 512];
    short* BsW0 = &Bs[w * 512];
    short* BsW1 = &Bs[2048 + w * 512];

    const int lrow = lane & 15;
    const int lk = (lane >> 4) * 8;

    for (int kt = 0; kt < KW; kt += 32) {
        const int ak = (kt < 1536 ? kt : kt - 1536) + c8;
        load_lds16(A2 + (size_t)(bm + r0) * KA + ak, AsW0);
        load_lds16(A2 + (size_t)(bm + 64 + r0) * KA + ak, AsW1);
        load_lds16(Wt + (size_t)(bn + r0) * KW + kt + c8, BsW0);
        load_lds16(Wt + (size_t)(bn + 64 + r0) * KW + kt + c8, BsW1);
        __syncthreads();

        short8_t af[4], bf[4];
#pragma unroll
        for (int i = 0; i < 4; ++i) {
            af[i] = *(const short8_t*)&As[(wm + i * 16 + lrow) * 32 + lk];
            bf[i] = *(const short8_t*)&Bs[(wn + i * 16 + lrow) * 32 + lk];
        }
#pragma unroll
        for (int i = 0; i < 4; ++i)
#pragma unroll
            for (int j = 0; j < 4; ++j)
                acc[i][j] = __builtin_amdgcn_mfma_f32_16x16x32_bf16(af[i], bf[j], acc[i][j], 0, 0, 0);
        __syncthreads();
    }

    const int rquad = (lane >> 4) * 4;
#pragma unroll
    for (int i = 0; i < 4; ++i) {
#pragma unroll
        for (int j = 0; j < 4; ++j) {
            const int col = bn + wn + j * 16 + lrow;
            const float bcol = bias[col];
#pragma unroll
            for (int r = 0; r < 4; ++r) {
                const size_t row = (size_t)(bm + wm + i * 16 + rquad + r);
                float v = acc[i][j][r] + bcol;
                if (MODE == 1) v = (attn[row * ldc + col] + v) * gamma[col];
                C[row * (size_t)ldc + col] = v;
            }
        }
    }
}

// Single GEMM: N=768 (6 col tiles), 384 blocks, XCD-swizzled.
template <int MODE>
__global__ __launch_bounds__(256) void gemm_mfma(
    const short* __restrict__ A2, const short* __restrict__ Wt,
    const float* __restrict__ bias, float* __restrict__ C,
    const float* __restrict__ attn, const float* __restrict__ gamma)
{
    const int bid = blockIdx.x;
    const int swz = (bid & 7) * 48 + (bid >> 3);
    gemm_body<MODE>(A2, Wt, bias, C, 768, swz & 63, swz >> 6, attn, gamma);
}

// Dual GEMM: two independent jobs in one dispatch. Each job count divisible by 8.
__global__ __launch_bounds__(256) void dual_gemm(
    const short* __restrict__ A0, const short* __restrict__ W0,
    const float* __restrict__ b0, float* __restrict__ C0, int ldc0, int cnt0,
    const short* __restrict__ A1, const short* __restrict__ W1,
    const float* __restrict__ b1, float* __restrict__ C1, int ldc1, int cnt1)
{
    int bid = blockIdx.x;
    const short *A2, *Wt; const float* bias; float* C; int ldc, cnt;
    if (bid < cnt0) { A2 = A0; Wt = W0; bias = b0; C = C0; ldc = ldc0; cnt = cnt0; }
    else { bid -= cnt0; A2 = A1; Wt = W1; bias = b1; C = C1; ldc = ldc1; cnt = cnt1; }
    const int q = cnt >> 3;
    const int swz = (bid & 7) * q + (bid >> 3);
    gemm_body<0>(A2, Wt, bias, C, ldc, swz & 63, swz >> 6, nullptr, nullptr);
}

// ---------------------------------------------------------------------------
// LayerNorm over 768 cols -> split-bf16 A2 only (no fp32 output).
// Safe when A2 overlays X (all reads complete before barrier; writes after).
// ---------------------------------------------------------------------------
__global__ __launch_bounds__(256) void ln_emit(
    const float* __restrict__ X, __hip_bfloat16* __restrict__ A2,
    const float* __restrict__ g, const float* __restrict__ beta)
{
    const int row = blockIdx.x;
    const float* x = X + (size_t)row * D_MODEL;
    const int t = threadIdx.x;
    float v0 = x[t], v1 = x[t + 256], v2 = x[t + 512];
    float s = v0 + v1 + v2;
    float s2 = v0 * v0 + v1 * v1 + v2 * v2;
#pragma unroll
    for (int m = 1; m < 64; m <<= 1) {
        s += __shfl_xor(s, m);
        s2 += __shfl_xor(s2, m);
    }
    __shared__ float red[8];
    const int wave = t >> 6, lane = t & 63;
    if (lane == 0) { red[wave] = s; red[wave + 4] = s2; }
    __syncthreads();
    s = red[0] + red[1] + red[2] + red[3];
    s2 = red[4] + red[5] + red[6] + red[7];
    const float mean = s * (1.f / 768.f);
    const float var = s2 * (1.f / 768.f) - mean * mean;
    const float rstd = rsqrtf(var + 1e-6f);
    float y0 = (v0 - mean) * rstd * g[t] + beta[t];
    float y1 = (v1 - mean) * rstd * g[t + 256] + beta[t + 256];
    float y2 = (v2 - mean) * rstd * g[t + 512] + beta[t + 512];
    __hip_bfloat16* arow = A2 + (size_t)row * 1536;
    __hip_bfloat16 h, l;
    f32_to_bf16_pair(y0, h, l); arow[t] = h;       arow[t + 768] = l;
    f32_to_bf16_pair(y1, h, l); arow[t + 256] = h; arow[t + 1024] = l;
    f32_to_bf16_pair(y2, h, l); arow[t + 512] = h; arow[t + 1280] = l;
}

// ---------------------------------------------------------------------------
// Two fp32 (M x 768) tensors -> split-bf16 A2 (M x 1536 = [hi | lo])
// ---------------------------------------------------------------------------
__global__ __launch_bounds__(256) void convert_act2(
    const float* __restrict__ X0, __hip_bfloat16* __restrict__ D0,
    const float* __restrict__ X1, __hip_bfloat16* __restrict__ D1)
{
    const int i = blockIdx.x * 256 + threadIdx.x;  // over 2*MTOT*192 float4s
    const int sel = i / (MTOT * 192);
    const int r = i - sel * (MTOT * 192);
    const float* X = sel ? X1 : X0;
    __hip_bfloat16* A2 = sel ? D1 : D0;
    const int row = r / 192;
    const int c4 = (r - row * 192) * 4;
    const float4 v = *(const float4*)(X + (size_t)row * 768 + c4);
    __hip_bfloat16* arow = A2 + (size_t)row * 1536;
    __hip_bfloat16 h, l;
    f32_to_bf16_pair(v.x, h, l); arow[c4 + 0] = h; arow[768 + c4 + 0] = l;
    f32_to_bf16_pair(v.y, h, l); arow[c4 + 1] = h; arow[768 + c4 + 1] = l;
    f32_to_bf16_pair(v.z, h, l); arow[c4 + 2] = h; arow[768 + c4 + 2] = l;
    f32_to_bf16_pair(v.w, h, l); arow[c4 + 3] = h; arow[768 + c4 + 3] = l;
}

// ---------------------------------------------------------------------------
// 6 big weights W(768x768 fp32) -> W2t(768x2304 bf16) = [Wh;Wh;Wl] transposed.
// ---------------------------------------------------------------------------
__global__ __launch_bounds__(256) void convert_w6(
    const float* __restrict__ w0, const float* __restrict__ w1,
    const float* __restrict__ w2, const float* __restrict__ w3,
    const float* __restrict__ w4, const float* __restrict__ w5,
    __hip_bfloat16* __restrict__ Wall)
{
    const int wi = blockIdx.y;
    const float* W = (wi == 0) ? w0 : (wi == 1) ? w1 : (wi == 2) ? w2
                   : (wi == 3) ? w3 : (wi == 4) ? w4 : w5;
    __hip_bfloat16* Wt = Wall + (size_t)wi * 768 * 2304;

    __shared__ float tile[32][33];
    const int tk0 = (blockIdx.x / 24) * 32;
    const int tn0 = (blockIdx.x % 24) * 32;
    const int t = threadIdx.x;
#pragma unroll
    for (int r = 0; r < 4; ++r) {
        const int row = r * 8 + (t >> 5);
        const int col = t & 31;
        tile[row][col] = W[(size_t)(tk0 + row) * 768 + tn0 + col];
    }
    __syncthreads();
    const int n = t >> 3;
    const int kq = (t & 7) * 4;
    __hip_bfloat16* dst = Wt + (size_t)(tn0 + n) * 2304 + tk0 + kq;
#pragma unroll
    for (int u = 0; u < 4; ++u) {
        __hip_bfloat16 h, l;
        f32_to_bf16_pair(tile[kq + u][n], h, l);
        dst[u] = h;
        dst[768 + u] = h;
        dst[1536 + u] = l;
    }
}

// ---------------------------------------------------------------------------
// Combined offset|aw weights: Woff(768x128), Wa(768x64) -> Wt(256 x 2304),
// cols 192..255 zero. Also builds combined bias (256). Two pairs (cross, self).
// ---------------------------------------------------------------------------
__global__ __launch_bounds__(256) void convert_offa(
    const float* __restrict__ Woff_c, const float* __restrict__ Wa_c,
    const float* __restrict__ boff_c, const float* __restrict__ ba_c,
    const float* __restrict__ Woff_s, const float* __restrict__ Wa_s,
    const float* __restrict__ boff_s, const float* __restrict__ ba_s,
    __hip_bfloat16* __restrict__ Wc, __hip_bfloat16* __restrict__ Ws,
    float* __restrict__ bias_c, float* __restrict__ bias_s)
{
    const int i = blockIdx.x * 256 + threadIdx.x;  // 2*256*192
    if (i >= 2 * 256 * 192) return;
    const int pair = i / (256 * 192);
    const int r = i - pair * (256 * 192);
    const int n = r / 192;
    const int k0 = (r - n * 192) * 4;
    const float* Woff = pair ? Woff_s : Woff_c;
    const float* Wa = pair ? Wa_s : Wa_c;
    __hip_bfloat16* dst = pair ? Ws : Wc;
#pragma unroll
    for (int u = 0; u < 4; ++u) {
        const int k = k0 + u;
        float v = (n < 128) ? Woff[(size_t)k * 128 + n]
                : (n < 192) ? Wa[(size_t)k * 64 + (n - 128)] : 0.f;
        __hip_bfloat16 h, l;
        f32_to_bf16_pair(v, h, l);
        __hip_bfloat16* row = dst + (size_t)n * 2304;
        row[k] = h; row[768 + k] = h; row[1536 + k] = l;
    }
    if (k0 == 0) {
        const float* boff = pair ? boff_s : boff_c;
        const float* ba = pair ? ba_s : ba_c;
        float* bias = pair ? bias_s : bias_c;
        bias[n] = (n < 128) ? boff[n] : (n < 192) ? ba[n - 128] : 0.f;
    }
}

// ---------------------------------------------------------------------------
// softmax over P=4 + sampling loc. Reads combined (M x 256): off at 0, aw at 128.
// ---------------------------------------------------------------------------
__global__ __launch_bounds__(256) void offaw_post(
    const float* __restrict__ offc,
    float* __restrict__ loc, float* __restrict__ aw)
{
    const int i = blockIdx.x * 256 + threadIdx.x;
    if (i >= MTOT * NH) return;
    const int h = i & (NH - 1);
    const int bq = i >> 4;
    const int q = bq & (LQ - 1);

    const float* orow = offc + (size_t)bq * 256 + h * 8;
    const float* arow = offc + (size_t)bq * 256 + 128 + h * 4;

    float a0 = arow[0], a1 = arow[1], a2 = arow[2], a3 = arow[3];
    float mx = fmaxf(fmaxf(a0, a1), fmaxf(a2, a3));
    float e0 = expf(a0 - mx), e1 = expf(a1 - mx), e2 = expf(a2 - mx), e3 = expf(a3 - mx);
    float r = 1.f / (e0 + e1 + e2 + e3);

    const float refx = ((q & 63) + 0.5f) * (1.f / 64.f);
    const float refy = ((q >> 6) + 0.5f) * (1.f / 64.f);
#pragma unroll
    for (int p = 0; p < 4; ++p) {
        loc[(size_t)i * 8 + p * 2 + 0] = refx + orow[p * 2 + 0] * (1.f / 64.f);
        loc[(size_t)i * 8 + p * 2 + 1] = refy + orow[p * 2 + 1] * (1.f / 64.f);
    }
    aw[(size_t)i * 4 + 0] = e0 * r;
    aw[(size_t)i * 4 + 1] = e1 * r;
    aw[(size_t)i * 4 + 2] = e2 * r;
    aw[(size_t)i * 4 + 3] = e3 * r;
}

// ---------------------------------------------------------------------------
// Bilinear sampling, float4 over d, fused split-bf16 output (GEMM A operand).
// Thread -> (bqh, c) with c in [0,12): d = 4c..4c+3.
// ---------------------------------------------------------------------------
__global__ __launch_bounds__(256) void sample_f4(
    const float* __restrict__ value, const float* __restrict__ loc,
    const float* __restrict__ aw, __hip_bfloat16* __restrict__ A2)
{
    const int idx = blockIdx.x * 256 + threadIdx.x;  // MTOT*NH*12
    const int bqh = idx / 12;
    const int c = idx - bqh * 12;
    const int d0 = c * 4;
    const int h = bqh & (NH - 1);
    const int bq = bqh >> 4;
    const int b = bq >> 12;

    const float4 l01 = *(const float4*)(loc + (size_t)bqh * 8);
    const float4 l23 = *(const float4*)(loc + (size_t)bqh * 8 + 4);
    const float4 w4 = *(const float4*)(aw + (size_t)bqh * 4);
    const float lx[4] = {l01.x, l01.z, l23.x, l23.z};
    const float ly[4] = {l01.y, l01.w, l23.y, l23.w};
    const float wp4[4] = {w4.x, w4.y, w4.z, w4.w};

    const float* vbase = value + (size_t)b * LQ * D_MODEL + h * DH + d0;

    float4 acc = {0.f, 0.f, 0.f, 0.f};
#pragma unroll
    for (int p = 0; p < 4; ++p) {
        const float x = lx[p] * 64.f - 0.5f;
        const float y = ly[p] * 64.f - 0.5f;
        const float xf = floorf(x), yf = floorf(y);
        const float wx1 = x - xf, wy1 = y - yf;
        const float wx0 = 1.f - wx1, wy0 = 1.f - wy1;
        const int x0 = (int)xf, y0 = (int)yf;
        const int x1 = x0 + 1, y1 = y0 + 1;
        const float wp = wp4[p];
        const bool vx0 = (x0 >= 0) && (x0 < 64);
        const bool vx1 = (x1 >= 0) && (x1 < 64);
        const bool vy0 = (y0 >= 0) && (y0 < 64);
        const bool vy1 = (y1 >= 0) && (y1 < 64);
        const float cw[4] = {wp * wx0 * wy0, wp * wx1 * wy0, wp * wx0 * wy1, wp * wx1 * wy1};
        const bool cv[4] = {vx0 && vy0, vx1 && vy0, vx0 && vy1, vx1 && vy1};
        const int cxy[4][2] = {{x0, y0}, {x1, y0}, {x0, y1}, {x1, y1}};
#pragma unroll
        for (int k = 0; k < 4; ++k) {
            if (cv[k]) {
                const float4 g = *(const float4*)(vbase + (size_t)(cxy[k][1] * 64 + cxy[k][0]) * D_MODEL);
                acc.x += cw[k] * g.x; acc.y += cw[k] * g.y;
                acc.z += cw[k] * g.z; acc.w += cw[k] * g.w;
            }
        }
    }

    __hip_bfloat16* arow = A2 + (size_t)bq * 1536 + h * DH + d0;
    __hip_bfloat16 hi[4], lo[4];
    f32_to_bf16_pair(acc.x, hi[0], lo[0]);
    f32_to_bf16_pair(acc.y, hi[1], lo[1]);
    f32_to_bf16_pair(acc.z, hi[2], lo[2]);
    f32_to_bf16_pair(acc.w, hi[3], lo[3]);
    *(uint2*)arow = *(uint2*)hi;
    *(uint2*)(arow + 768) = *(uint2*)lo;
}

// ---------------------------------------------------------------------------
extern "C" void kernel_launch(void* const* d_in, const int* in_sizes, int n_in,
                              void* d_out, int out_size, void* d_ws, size_t ws_size,
                              hipStream_t stream)
{
    const float* query   = (const float*)d_in[0];
    const float* feat    = (const float*)d_in[1];
    const float* qn_W    = (const float*)d_in[4];
    const float* qn_b    = (const float*)d_in[5];
    const float* qn_g    = (const float*)d_in[6];
    const float* qn_beta = (const float*)d_in[7];
    const float* fn_W    = (const float*)d_in[8];
    const float* fn_b    = (const float*)d_in[9];
    const float* fn_g    = (const float*)d_in[10];
    const float* fn_beta = (const float*)d_in[11];
    const float* nm_g    = (const float*)d_in[12];
    const float* nm_beta = (const float*)d_in[13];
    const float* gamma1  = (const float*)d_in[14];
    const float* c_Wv    = (const float*)d_in[15];
    const float* c_bv    = (const float*)d_in[16];
    const float* c_Woff  = (const float*)d_in[17];
    const float* c_boff  = (const float*)d_in[18];
    const float* c_Wa    = (const float*)d_in[19];
    const float* c_ba    = (const float*)d_in[20];
    const float* c_Wo    = (const float*)d_in[21];
    const float* c_bo    = (const float*)d_in[22];
    const float* s_Wv    = (const float*)d_in[23];
    const float* s_bv    = (const float*)d_in[24];
    const float* s_Woff  = (const float*)d_in[25];
    const float* s_boff  = (const float*)d_in[26];
    const float* s_Wa    = (const float*)d_in[27];
    const float* s_ba    = (const float*)d_in[28];
    const float* s_Wo    = (const float*)d_in[29];
    const float* s_bo    = (const float*)d_in[30];

    float* ws = (float*)d_ws;
    const size_t SZ = (size_t)MTOT * D_MODEL;  // 6291456 floats (= 1536 bf16/row)
    float* buf0 = ws;            // qn pre-LN fp32; later offc (M x 256)
    float* buf1 = ws + SZ;       // fn pre-LN fp32; overlaid by A2fn, then A2samp
    float* buf2 = ws + 2 * SZ;   // feat-raw A2 (pre G1); then val fp32
    float* buf3 = ws + 3 * SZ;   // attn fp32 (live to the end)
    __hip_bfloat16* A2X = (__hip_bfloat16*)(ws + 4 * SZ);  // query-raw -> qn -> attn1
    float* loc    = ws + 5 * SZ;                    // MTOT*128
    float* aws    = loc + (size_t)MTOT * 128;       // MTOT*64
    float* bias_c = aws + (size_t)MTOT * 64;        // 256
    float* bias_s = bias_c + 256;                   // 256
    __hip_bfloat16* W6 = (__hip_bfloat16*)(bias_s + 256);
    __hip_bfloat16* W_qn  = W6 + (size_t)0 * 768 * 2304;
    __hip_bfloat16* W_fn  = W6 + (size_t)1 * 768 * 2304;
    __hip_bfloat16* W_cWv = W6 + (size_t)2 * 768 * 2304;
    __hip_bfloat16* W_cWo = W6 + (size_t)3 * 768 * 2304;
    __hip_bfloat16* W_sWv = W6 + (size_t)4 * 768 * 2304;
    __hip_bfloat16* W_sWo = W6 + (size_t)5 * 768 * 2304;
    __hip_bfloat16* Woffa_c = W6 + (size_t)6 * 768 * 2304;      // 256 x 2304
    __hip_bfloat16* Woffa_s = Woffa_c + (size_t)256 * 2304;

    __hip_bfloat16* A2feat = (__hip_bfloat16*)buf2;
    __hip_bfloat16* A2fn   = (__hip_bfloat16*)buf1;  // LN overlay (safe: reads pre-barrier)
    __hip_bfloat16* A2samp = (__hip_bfloat16*)buf1;
    float* offc = buf0;

    float* out = (float*)d_out;
    const dim3 blk(256);

    // ---- weight + activation conversion ----
    convert_w6<<<dim3(576, 6), blk, 0, stream>>>(qn_W, fn_W, c_Wv, c_Wo, s_Wv, s_Wo, W6);
    convert_offa<<<384, blk, 0, stream>>>(c_Woff, c_Wa, c_boff, c_ba,
                                          s_Woff, s_Wa, s_boff, s_ba,
                                          Woffa_c, Woffa_s, bias_c, bias_s);
    convert_act2<<<12288, blk, 0, stream>>>(query, A2X, feat, A2feat);

    // ---- cross attention ----
    // G1: qn = query@qn_W + b ; fn = feat@fn_W + b
    dual_gemm<<<768, blk, 0, stream>>>((const short*)A2X, (const short*)W_qn, qn_b, buf0, 768, 384,
                                       (const short*)A2feat, (const short*)W_fn, fn_b, buf1, 768, 384);
    ln_emit<<<MTOT, blk, 0, stream>>>(buf0, A2X, qn_g, qn_beta);          // qn -> A2X
    ln_emit<<<MTOT, blk, 0, stream>>>(buf1, A2fn, fn_g, fn_beta);         // fn -> buf1 (overlay)
    // G2: val = fn@c_Wv ; offc = qn@[c_Woff|c_Wa]
    dual_gemm<<<512, blk, 0, stream>>>((const short*)A2fn, (const short*)W_cWv, c_bv, buf2, 768, 384,
                                       (const short*)A2X, (const short*)Woffa_c, bias_c, offc, 256, 128);
    offaw_post<<<(MTOT * NH + 255) / 256, blk, 0, stream>>>(offc, loc, aws);
    sample_f4<<<MTOT * NH * 12 / 256, blk, 0, stream>>>(buf2, loc, aws, A2samp);
    gemm_mfma<0><<<384, blk, 0, stream>>>((const short*)A2samp, (const short*)W_cWo, c_bo, buf3, nullptr, nullptr);

    // ---- self attention ----
    ln_emit<<<MTOT, blk, 0, stream>>>(buf3, A2X, nm_g, nm_beta);          // attn1 -> A2X
    // G4: val = attn1@s_Wv ; offc = attn1@[s_Woff|s_Wa]
    dual_gemm<<<512, blk, 0, stream>>>((const short*)A2X, (const short*)W_sWv, s_bv, buf2, 768, 384,
                                       (const short*)A2X, (const short*)Woffa_s, bias_s, offc, 256, 128);
    offaw_post<<<(MTOT * NH + 255) / 256, blk, 0, stream>>>(offc, loc, aws);
    sample_f4<<<MTOT * NH * 12 / 256, blk, 0, stream>>>(buf2, loc, aws, A2samp);
    // final: out = gamma1 * (attn + samp@s_Wo + s_bo)
    gemm_mfma<1><<<384, blk, 0, stream>>>((const short*)A2samp, (const short*)W_sWo, s_bo, out, buf3, gamma1);
}

// Round 5
// 399.960 us; speedup vs baseline: 3.7742x; 1.4439x over previous
//
#include <hip/hip_runtime.h>
#include <hip/hip_bf16.h>
#include <math.h>

#define D_MODEL 768
#define NH 16
#define DH 48
#define NP 4
#define LQ 4096
#define BB 2
#define MTOT (BB * LQ)  // 8192

typedef __attribute__((ext_vector_type(8))) _Float16 half8_t;
typedef __attribute__((ext_vector_type(4))) float floatx4;

__device__ __forceinline__ void load_lds16(const void* g, void* l) {
    __builtin_amdgcn_global_load_lds((const __attribute__((address_space(1))) void*)g,
                                     (__attribute__((address_space(3))) void*)l, 16, 0, 0);
}

// ---------------------------------------------------------------------------
// fp16 MFMA GEMM tile body. A: (M x 768 fp16); Wt: (ldc x 768 fp16, transposed).
// 128x128 tile at (tm, tn), BK=32, 4 waves (2x2), 4x4 16x16x32 MFMA per wave.
// MODE 0: C = acc + bias ; MODE 1: C = gamma[col]*(attn[row,col] + acc + bias)
// ---------------------------------------------------------------------------
template <int MODE>
__device__ __forceinline__ void gemm_body(
    const _Float16* __restrict__ A, const _Float16* __restrict__ Wt,
    const float* __restrict__ bias, float* __restrict__ C, int ldc,
    int tm, int tn,
    const float* __restrict__ attn, const float* __restrict__ gamma)
{
    constexpr int K = 768;
    __shared__ _Float16 As[128 * 32];
    __shared__ _Float16 Bs[128 * 32];

    const int bm = tm * 128, bn = tn * 128;
    const int t = threadIdx.x;
    const int lane = t & 63;
    const int w = t >> 6;
    const int wm = (w >> 1) * 64, wn = (w & 1) * 64;

    floatx4 acc[4][4] = {};

    const int r0 = t >> 2;           // 0..63
    const int c8 = (t & 3) * 8;      // 0/8/16/24
    _Float16* AsW0 = &As[w * 512];   // wave-uniform LDS bases
    _Float16* AsW1 = &As[2048 + w * 512];
    _Float16* BsW0 = &Bs[w * 512];
    _Float16* BsW1 = &Bs[2048 + w * 512];

    const int lrow = lane & 15;
    const int lk = (lane >> 4) * 8;

    for (int kt = 0; kt < K; kt += 32) {
        load_lds16(A + (size_t)(bm + r0) * K + kt + c8, AsW0);
        load_lds16(A + (size_t)(bm + 64 + r0) * K + kt + c8, AsW1);
        load_lds16(Wt + (size_t)(bn + r0) * K + kt + c8, BsW0);
        load_lds16(Wt + (size_t)(bn + 64 + r0) * K + kt + c8, BsW1);
        __syncthreads();  // drains vmcnt before LDS reads

        half8_t af[4], bf[4];
#pragma unroll
        for (int i = 0; i < 4; ++i) {
            af[i] = *(const half8_t*)&As[(wm + i * 16 + lrow) * 32 + lk];
            bf[i] = *(const half8_t*)&Bs[(wn + i * 16 + lrow) * 32 + lk];
        }
#pragma unroll
        for (int i = 0; i < 4; ++i)
#pragma unroll
            for (int j = 0; j < 4; ++j)
                acc[i][j] = __builtin_amdgcn_mfma_f32_16x16x32_f16(af[i], bf[j], acc[i][j], 0, 0, 0);
        __syncthreads();
    }

    // epilogue: C/D layout col=lane&15, row=(lane>>4)*4+reg
    const int rquad = (lane >> 4) * 4;
#pragma unroll
    for (int i = 0; i < 4; ++i) {
#pragma unroll
        for (int j = 0; j < 4; ++j) {
            const int col = bn + wn + j * 16 + lrow;
            const float bcol = bias[col];
#pragma unroll
            for (int r = 0; r < 4; ++r) {
                const size_t row = (size_t)(bm + wm + i * 16 + rquad + r);
                float v = acc[i][j][r] + bcol;
                if (MODE == 1) v = (attn[row * ldc + col] + v) * gamma[col];
                C[row * (size_t)ldc + col] = v;
            }
        }
    }
}

// Single GEMM: N=768 (6 col tiles), 384 blocks, XCD-swizzled.
template <int MODE>
__global__ __launch_bounds__(256) void gemm_mfma(
    const _Float16* __restrict__ A, const _Float16* __restrict__ Wt,
    const float* __restrict__ bias, float* __restrict__ C,
    const float* __restrict__ attn, const float* __restrict__ gamma)
{
    const int bid = blockIdx.x;
    const int swz = (bid & 7) * 48 + (bid >> 3);
    gemm_body<MODE>(A, Wt, bias, C, 768, swz & 63, swz >> 6, attn, gamma);
}

// Dual GEMM: two independent jobs in one dispatch. Each job count divisible by 8.
__global__ __launch_bounds__(256) void dual_gemm(
    const _Float16* __restrict__ A0, const _Float16* __restrict__ W0,
    const float* __restrict__ b0, float* __restrict__ C0, int ldc0, int cnt0,
    const _Float16* __restrict__ A1, const _Float16* __restrict__ W1,
    const float* __restrict__ b1, float* __restrict__ C1, int ldc1, int cnt1)
{
    int bid = blockIdx.x;
    const _Float16 *A, *Wt; const float* bias; float* C; int ldc, cnt;
    if (bid < cnt0) { A = A0; Wt = W0; bias = b0; C = C0; ldc = ldc0; cnt = cnt0; }
    else { bid -= cnt0; A = A1; Wt = W1; bias = b1; C = C1; ldc = ldc1; cnt = cnt1; }
    const int q = cnt >> 3;
    const int swz = (bid & 7) * q + (bid >> 3);
    gemm_body<0>(A, Wt, bias, C, ldc, swz & 63, swz >> 6, nullptr, nullptr);
}

// ---------------------------------------------------------------------------
// LayerNorm over 768 cols -> fp16 operand. Dual-input variant: grid 2*MTOT.
// ---------------------------------------------------------------------------
__device__ __forceinline__ void ln_body(
    const float* __restrict__ X, _Float16* __restrict__ A,
    const float* __restrict__ g, const float* __restrict__ beta, int row)
{
    const float* x = X + (size_t)row * D_MODEL;
    const int t = threadIdx.x;
    float v0 = x[t], v1 = x[t + 256], v2 = x[t + 512];
    float s = v0 + v1 + v2;
    float s2 = v0 * v0 + v1 * v1 + v2 * v2;
#pragma unroll
    for (int m = 1; m < 64; m <<= 1) {
        s += __shfl_xor(s, m);
        s2 += __shfl_xor(s2, m);
    }
    __shared__ float red[8];
    const int wave = t >> 6, lane = t & 63;
    if (lane == 0) { red[wave] = s; red[wave + 4] = s2; }
    __syncthreads();
    s = red[0] + red[1] + red[2] + red[3];
    s2 = red[4] + red[5] + red[6] + red[7];
    const float mean = s * (1.f / 768.f);
    const float var = s2 * (1.f / 768.f) - mean * mean;
    const float rstd = rsqrtf(var + 1e-6f);
    _Float16* arow = A + (size_t)row * D_MODEL;
    arow[t]       = (_Float16)((v0 - mean) * rstd * g[t] + beta[t]);
    arow[t + 256] = (_Float16)((v1 - mean) * rstd * g[t + 256] + beta[t + 256]);
    arow[t + 512] = (_Float16)((v2 - mean) * rstd * g[t + 512] + beta[t + 512]);
}

__global__ __launch_bounds__(256) void ln2_emit(
    const float* __restrict__ X0, _Float16* __restrict__ A0,
    const float* __restrict__ g0, const float* __restrict__ b0,
    const float* __restrict__ X1, _Float16* __restrict__ A1,
    const float* __restrict__ g1, const float* __restrict__ b1)
{
    const int row = blockIdx.x;
    if (row < MTOT) ln_body(X0, A0, g0, b0, row);
    else            ln_body(X1, A1, g1, b1, row - MTOT);
}

__global__ __launch_bounds__(256) void ln_emit(
    const float* __restrict__ X, _Float16* __restrict__ A,
    const float* __restrict__ g, const float* __restrict__ beta)
{
    ln_body(X, A, g, beta, blockIdx.x);
}

// ---------------------------------------------------------------------------
// Two fp32 (M x 768) tensors -> fp16 (M x 768)
// ---------------------------------------------------------------------------
__global__ __launch_bounds__(256) void convert_act2(
    const float* __restrict__ X0, _Float16* __restrict__ D0,
    const float* __restrict__ X1, _Float16* __restrict__ D1)
{
    const int i = blockIdx.x * 256 + threadIdx.x;  // over 2*MTOT*192 float4s
    const int sel = i / (MTOT * 192);
    const int r = i - sel * (MTOT * 192);
    const float* X = sel ? X1 : X0;
    _Float16* D = sel ? D1 : D0;
    const int c4 = r * 4;
    const float4 v = *(const float4*)(X + (size_t)c4);
    _Float16 o[4] = {(_Float16)v.x, (_Float16)v.y, (_Float16)v.z, (_Float16)v.w};
    *(uint2*)(D + (size_t)c4) = *(uint2*)o;
}

// ---------------------------------------------------------------------------
// 6 big weights W(768x768 fp32) -> Wt(768x768 fp16, transposed)
// ---------------------------------------------------------------------------
__global__ __launch_bounds__(256) void convert_w6(
    const float* __restrict__ w0, const float* __restrict__ w1,
    const float* __restrict__ w2, const float* __restrict__ w3,
    const float* __restrict__ w4, const float* __restrict__ w5,
    _Float16* __restrict__ Wall)
{
    const int wi = blockIdx.y;
    const float* W = (wi == 0) ? w0 : (wi == 1) ? w1 : (wi == 2) ? w2
                   : (wi == 3) ? w3 : (wi == 4) ? w4 : w5;
    _Float16* Wt = Wall + (size_t)wi * 768 * 768;

    __shared__ float tile[32][33];
    const int tk0 = (blockIdx.x / 24) * 32;
    const int tn0 = (blockIdx.x % 24) * 32;
    const int t = threadIdx.x;
#pragma unroll
    for (int r = 0; r < 4; ++r) {
        const int row = r * 8 + (t >> 5);
        const int col = t & 31;
        tile[row][col] = W[(size_t)(tk0 + row) * 768 + tn0 + col];
    }
    __syncthreads();
    const int n = t >> 3;
    const int kq = (t & 7) * 4;
    _Float16* dst = Wt + (size_t)(tn0 + n) * 768 + tk0 + kq;
#pragma unroll
    for (int u = 0; u < 4; ++u) dst[u] = (_Float16)tile[kq + u][n];
}

// ---------------------------------------------------------------------------
// Combined offset|aw weights -> Wt(256 x 768 fp16, transposed), rows 192..255
// zero; combined bias (256). Two pairs (cross, self).
// ---------------------------------------------------------------------------
__global__ __launch_bounds__(256) void convert_offa(
    const float* __restrict__ Woff_c, const float* __restrict__ Wa_c,
    const float* __restrict__ boff_c, const float* __restrict__ ba_c,
    const float* __restrict__ Woff_s, const float* __restrict__ Wa_s,
    const float* __restrict__ boff_s, const float* __restrict__ ba_s,
    _Float16* __restrict__ Wc, _Float16* __restrict__ Ws,
    float* __restrict__ bias_c, float* __restrict__ bias_s)
{
    const int i = blockIdx.x * 256 + threadIdx.x;  // 2*256*192
    if (i >= 2 * 256 * 192) return;
    const int pair = i / (256 * 192);
    const int r = i - pair * (256 * 192);
    const int n = r / 192;
    const int k0 = (r - n * 192) * 4;
    const float* Woff = pair ? Woff_s : Woff_c;
    const float* Wa = pair ? Wa_s : Wa_c;
    _Float16* dst = pair ? Ws : Wc;
    _Float16* row = dst + (size_t)n * 768;
#pragma unroll
    for (int u = 0; u < 4; ++u) {
        const int k = k0 + u;
        float v = (n < 128) ? Woff[(size_t)k * 128 + n]
                : (n < 192) ? Wa[(size_t)k * 64 + (n - 128)] : 0.f;
        row[k] = (_Float16)v;
    }
    if (k0 == 0) {
        const float* boff = pair ? boff_s : boff_c;
        const float* ba = pair ? ba_s : ba_c;
        float* bias = pair ? bias_s : bias_c;
        bias[n] = (n < 128) ? boff[n] : (n < 192) ? ba[n - 128] : 0.f;
    }
}

// ---------------------------------------------------------------------------
// softmax over P=4 + sampling loc. Reads combined (M x 256): off at 0, aw at 128.
// ---------------------------------------------------------------------------
__global__ __launch_bounds__(256) void offaw_post(
    const float* __restrict__ offc,
    float* __restrict__ loc, float* __restrict__ aw)
{
    const int i = blockIdx.x * 256 + threadIdx.x;
    if (i >= MTOT * NH) return;
    const int h = i & (NH - 1);
    const int bq = i >> 4;
    const int q = bq & (LQ - 1);

    const float* orow = offc + (size_t)bq * 256 + h * 8;
    const float* arow = offc + (size_t)bq * 256 + 128 + h * 4;

    float a0 = arow[0], a1 = arow[1], a2 = arow[2], a3 = arow[3];
    float mx = fmaxf(fmaxf(a0, a1), fmaxf(a2, a3));
    float e0 = expf(a0 - mx), e1 = expf(a1 - mx), e2 = expf(a2 - mx), e3 = expf(a3 - mx);
    float r = 1.f / (e0 + e1 + e2 + e3);

    const float refx = ((q & 63) + 0.5f) * (1.f / 64.f);
    const float refy = ((q >> 6) + 0.5f) * (1.f / 64.f);
#pragma unroll
    for (int p = 0; p < 4; ++p) {
        loc[(size_t)i * 8 + p * 2 + 0] = refx + orow[p * 2 + 0] * (1.f / 64.f);
        loc[(size_t)i * 8 + p * 2 + 1] = refy + orow[p * 2 + 1] * (1.f / 64.f);
    }
    aw[(size_t)i * 4 + 0] = e0 * r;
    aw[(size_t)i * 4 + 1] = e1 * r;
    aw[(size_t)i * 4 + 2] = e2 * r;
    aw[(size_t)i * 4 + 3] = e3 * r;
}

// ---------------------------------------------------------------------------
// Bilinear sampling, float4 over d, fp16 output (GEMM A operand).
// Thread -> (bqh, c) with c in [0,12): d = 4c..4c+3.
// ---------------------------------------------------------------------------
__global__ __launch_bounds__(256) void sample_f4(
    const float* __restrict__ value, const float* __restrict__ loc,
    const float* __restrict__ aw, _Float16* __restrict__ A)
{
    const int idx = blockIdx.x * 256 + threadIdx.x;  // MTOT*NH*12
    const int bqh = idx / 12;
    const int c = idx - bqh * 12;
    const int d0 = c * 4;
    const int h = bqh & (NH - 1);
    const int bq = bqh >> 4;
    const int b = bq >> 12;

    const float4 l01 = *(const float4*)(loc + (size_t)bqh * 8);
    const float4 l23 = *(const float4*)(loc + (size_t)bqh * 8 + 4);
    const float4 w4 = *(const float4*)(aw + (size_t)bqh * 4);
    const float lx[4] = {l01.x, l01.z, l23.x, l23.z};
    const float ly[4] = {l01.y, l01.w, l23.y, l23.w};
    const float wp4[4] = {w4.x, w4.y, w4.z, w4.w};

    const float* vbase = value + (size_t)b * LQ * D_MODEL + h * DH + d0;

    float4 acc = {0.f, 0.f, 0.f, 0.f};
#pragma unroll
    for (int p = 0; p < 4; ++p) {
        const float x = lx[p] * 64.f - 0.5f;
        const float y = ly[p] * 64.f - 0.5f;
        const float xf = floorf(x), yf = floorf(y);
        const float wx1 = x - xf, wy1 = y - yf;
        const float wx0 = 1.f - wx1, wy0 = 1.f - wy1;
        const int x0 = (int)xf, y0 = (int)yf;
        const int x1 = x0 + 1, y1 = y0 + 1;
        const float wp = wp4[p];
        const bool vx0 = (x0 >= 0) && (x0 < 64);
        const bool vx1 = (x1 >= 0) && (x1 < 64);
        const bool vy0 = (y0 >= 0) && (y0 < 64);
        const bool vy1 = (y1 >= 0) && (y1 < 64);
        const float cw[4] = {wp * wx0 * wy0, wp * wx1 * wy0, wp * wx0 * wy1, wp * wx1 * wy1};
        const bool cv[4] = {vx0 && vy0, vx1 && vy0, vx0 && vy1, vx1 && vy1};
        const int cxy[4][2] = {{x0, y0}, {x1, y0}, {x0, y1}, {x1, y1}};
#pragma unroll
        for (int k = 0; k < 4; ++k) {
            if (cv[k]) {
                const float4 g = *(const float4*)(vbase + (size_t)(cxy[k][1] * 64 + cxy[k][0]) * D_MODEL);
                acc.x += cw[k] * g.x; acc.y += cw[k] * g.y;
                acc.z += cw[k] * g.z; acc.w += cw[k] * g.w;
            }
        }
    }

    _Float16* arow = A + (size_t)bq * D_MODEL + h * DH + d0;
    _Float16 o[4] = {(_Float16)acc.x, (_Float16)acc.y, (_Float16)acc.z, (_Float16)acc.w};
    *(uint2*)arow = *(uint2*)o;
}

// ---------------------------------------------------------------------------
extern "C" void kernel_launch(void* const* d_in, const int* in_sizes, int n_in,
                              void* d_out, int out_size, void* d_ws, size_t ws_size,
                              hipStream_t stream)
{
    const float* query   = (const float*)d_in[0];
    const float* feat    = (const float*)d_in[1];
    const float* qn_W    = (const float*)d_in[4];
    const float* qn_b    = (const float*)d_in[5];
    const float* qn_g    = (const float*)d_in[6];
    const float* qn_beta = (const float*)d_in[7];
    const float* fn_W    = (const float*)d_in[8];
    const float* fn_b    = (const float*)d_in[9];
    const float* fn_g    = (const float*)d_in[10];
    const float* fn_beta = (const float*)d_in[11];
    const float* nm_g    = (const float*)d_in[12];
    const float* nm_beta = (const float*)d_in[13];
    const float* gamma1  = (const float*)d_in[14];
    const float* c_Wv    = (const float*)d_in[15];
    const float* c_bv    = (const float*)d_in[16];
    const float* c_Woff  = (const float*)d_in[17];
    const float* c_boff  = (const float*)d_in[18];
    const float* c_Wa    = (const float*)d_in[19];
    const float* c_ba    = (const float*)d_in[20];
    const float* c_Wo    = (const float*)d_in[21];
    const float* c_bo    = (const float*)d_in[22];
    const float* s_Wv    = (const float*)d_in[23];
    const float* s_bv    = (const float*)d_in[24];
    const float* s_Woff  = (const float*)d_in[25];
    const float* s_boff  = (const float*)d_in[26];
    const float* s_Wa    = (const float*)d_in[27];
    const float* s_ba    = (const float*)d_in[28];
    const float* s_Wo    = (const float*)d_in[29];
    const float* s_bo    = (const float*)d_in[30];

    float* ws = (float*)d_ws;
    const size_t SZ = (size_t)MTOT * D_MODEL;  // 6291456 floats
    float* buf0 = ws;            // qn pre-LN fp32; later offc (M x 256)
    float* buf1 = ws + SZ;       // fn pre-LN fp32
    float* buf2 = ws + 2 * SZ;   // val fp32
    float* buf3 = ws + 3 * SZ;   // attn fp32 (live to the end)
    _Float16* slotA = (_Float16*)(ws + 4 * SZ);           // query-raw -> qn -> attn1 (M x 768 fp16)
    _Float16* slotB = (_Float16*)(ws + 4 * SZ + SZ / 2);  // feat-raw -> fn -> samp
    float* loc    = ws + 5 * SZ;                    // MTOT*128
    float* aws    = loc + (size_t)MTOT * 128;       // MTOT*64
    float* bias_c = aws + (size_t)MTOT * 64;        // 256
    float* bias_s = bias_c + 256;                   // 256
    _Float16* W6 = (_Float16*)(bias_s + 256);       // 6 x 768 x 768 fp16
    _Float16* W_qn  = W6 + (size_t)0 * 768 * 768;
    _Float16* W_fn  = W6 + (size_t)1 * 768 * 768;
    _Float16* W_cWv = W6 + (size_t)2 * 768 * 768;
    _Float16* W_cWo = W6 + (size_t)3 * 768 * 768;
    _Float16* W_sWv = W6 + (size_t)4 * 768 * 768;
    _Float16* W_sWo = W6 + (size_t)5 * 768 * 768;
    _Float16* Woffa_c = W6 + (size_t)6 * 768 * 768;       // 256 x 768
    _Float16* Woffa_s = Woffa_c + (size_t)256 * 768;

    float* out = (float*)d_out;
    const dim3 blk(256);

    // ---- weight + activation conversion ----
    convert_w6<<<dim3(576, 6), blk, 0, stream>>>(qn_W, fn_W, c_Wv, c_Wo, s_Wv, s_Wo, W6);
    convert_offa<<<384, blk, 0, stream>>>(c_Woff, c_Wa, c_boff, c_ba,
                                          s_Woff, s_Wa, s_boff, s_ba,
                                          Woffa_c, Woffa_s, bias_c, bias_s);
    convert_act2<<<12288, blk, 0, stream>>>(query, slotA, feat, slotB);

    // ---- cross attention ----
    // G1: qn = query@qn_W + b ; fn = feat@fn_W + b
    dual_gemm<<<768, blk, 0, stream>>>(slotA, W_qn, qn_b, buf0, 768, 384,
                                       slotB, W_fn, fn_b, buf1, 768, 384);
    ln2_emit<<<2 * MTOT, blk, 0, stream>>>(buf0, slotA, qn_g, qn_beta,
                                           buf1, slotB, fn_g, fn_beta);
    // G2: val = fn@c_Wv ; offc = qn@[c_Woff|c_Wa]
    dual_gemm<<<512, blk, 0, stream>>>(slotB, W_cWv, c_bv, buf2, 768, 384,
                                       slotA, Woffa_c, bias_c, buf0, 256, 128);
    offaw_post<<<(MTOT * NH + 255) / 256, blk, 0, stream>>>(buf0, loc, aws);
    sample_f4<<<MTOT * NH * 12 / 256, blk, 0, stream>>>(buf2, loc, aws, slotB);
    gemm_mfma<0><<<384, blk, 0, stream>>>(slotB, W_cWo, c_bo, buf3, nullptr, nullptr);

    // ---- self attention ----
    ln_emit<<<MTOT, blk, 0, stream>>>(buf3, slotA, nm_g, nm_beta);  // attn1 -> slotA
    // G4: val = attn1@s_Wv ; offc = attn1@[s_Woff|s_Wa]
    dual_gemm<<<512, blk, 0, stream>>>(slotA, W_sWv, s_bv, buf2, 768, 384,
                                       slotA, Woffa_s, bias_s, buf0, 256, 128);
    offaw_post<<<(MTOT * NH + 255) / 256, blk, 0, stream>>>(buf0, loc, aws);
    sample_f4<<<MTOT * NH * 12 / 256, blk, 0, stream>>>(buf2, loc, aws, slotB);
    // final: out = gamma1 * (attn + samp@s_Wo + s_bo)
    gemm_mfma<1><<<384, blk, 0, stream>>>(slotB, W_sWo, s_bo, out, buf3, gamma1);
}

// Round 6
// 382.413 us; speedup vs baseline: 3.9474x; 1.0459x over previous
//
#include <hip/hip_runtime.h>
#include <hip/hip_bf16.h>
#include <math.h>

#define D_MODEL 768
#define NH 16
#define DH 48
#define NP 4
#define LQ 4096
#define BB 2
#define MTOT (BB * LQ)  // 8192

typedef __attribute__((ext_vector_type(8))) _Float16 half8_t;
typedef __attribute__((ext_vector_type(4))) float floatx4;

__device__ __forceinline__ void load_lds16(const void* g, void* l) {
    __builtin_amdgcn_global_load_lds((const __attribute__((address_space(1))) void*)g,
                                     (__attribute__((address_space(3))) void*)l, 16, 0, 0);
}

// ---------------------------------------------------------------------------
// fp16 MFMA GEMM tile body, 2-phase double-buffered (T3-minimum recipe):
// STAGE(next) issued BEFORE compute(cur); ONE barrier per K-step drains it.
// A: (M x 768 fp16); Wt: (ldc x 768 fp16, transposed). 128x128 tile, BK=32,
// 4 waves (2x2), 4x4 16x16x32 MFMA per wave.
// MODE 0: C = acc + bias ; MODE 1: C = gamma[col]*(attn[row,col] + acc + bias)
// ---------------------------------------------------------------------------
template <int MODE>
__device__ __forceinline__ void gemm_body(
    const _Float16* __restrict__ A, const _Float16* __restrict__ Wt,
    const float* __restrict__ bias, float* __restrict__ C, int ldc,
    int tm, int tn,
    const float* __restrict__ attn, const float* __restrict__ gamma)
{
    constexpr int K = 768;
    constexpr int NT = K / 32;  // 24 K-steps
    __shared__ _Float16 As[2][128 * 32];   // 2 x 8 KB
    __shared__ _Float16 Bs[2][128 * 32];   // 2 x 8 KB

    const int bm = tm * 128, bn = tn * 128;
    const int t = threadIdx.x;
    const int lane = t & 63;
    const int w = t >> 6;
    const int wm = (w >> 1) * 64, wn = (w & 1) * 64;

    floatx4 acc[4][4] = {};

    const int r0 = t >> 2;           // 0..63
    const int c8 = (t & 3) * 8;      // 0/8/16/24
    const size_t arow0 = (size_t)(bm + r0) * K + c8;
    const size_t arow1 = (size_t)(bm + 64 + r0) * K + c8;
    const size_t brow0 = (size_t)(bn + r0) * K + c8;
    const size_t brow1 = (size_t)(bn + 64 + r0) * K + c8;

    const int lrow = lane & 15;
    const int lk = (lane >> 4) * 8;

    // prologue: stage K-step 0 into buffer 0
    load_lds16(A + arow0, &As[0][w * 512]);
    load_lds16(A + arow1, &As[0][2048 + w * 512]);
    load_lds16(Wt + brow0, &Bs[0][w * 512]);
    load_lds16(Wt + brow1, &Bs[0][2048 + w * 512]);
    __syncthreads();

    for (int ti = 0; ti < NT; ++ti) {
        const int cur = ti & 1;
        if (ti + 1 < NT) {  // stage next K-step into other buffer (flies under MFMA)
            const int kn = (ti + 1) * 32;
            const int nxt = cur ^ 1;
            load_lds16(A + arow0 + kn, &As[nxt][w * 512]);
            load_lds16(A + arow1 + kn, &As[nxt][2048 + w * 512]);
            load_lds16(Wt + brow0 + kn, &Bs[nxt][w * 512]);
            load_lds16(Wt + brow1 + kn, &Bs[nxt][2048 + w * 512]);
        }

        const _Float16* Ac = As[cur];
        const _Float16* Bc = Bs[cur];
        half8_t af[4], bf[4];
#pragma unroll
        for (int i = 0; i < 4; ++i) {
            af[i] = *(const half8_t*)&Ac[(wm + i * 16 + lrow) * 32 + lk];
            bf[i] = *(const half8_t*)&Bc[(wn + i * 16 + lrow) * 32 + lk];
        }
#pragma unroll
        for (int i = 0; i < 4; ++i)
#pragma unroll
            for (int j = 0; j < 4; ++j)
                acc[i][j] = __builtin_amdgcn_mfma_f32_16x16x32_f16(af[i], bf[j], acc[i][j], 0, 0, 0);

        if (ti + 1 < NT) __syncthreads();  // drains prefetch vmcnt + protects buffer reuse
    }

    // epilogue: C/D layout col=lane&15, row=(lane>>4)*4+reg
    const int rquad = (lane >> 4) * 4;
#pragma unroll
    for (int i = 0; i < 4; ++i) {
#pragma unroll
        for (int j = 0; j < 4; ++j) {
            const int col = bn + wn + j * 16 + lrow;
            const float bcol = bias[col];
#pragma unroll
            for (int r = 0; r < 4; ++r) {
                const size_t row = (size_t)(bm + wm + i * 16 + rquad + r);
                float v = acc[i][j][r] + bcol;
                if (MODE == 1) v = (attn[row * ldc + col] + v) * gamma[col];
                C[row * (size_t)ldc + col] = v;
            }
        }
    }
}

// Single GEMM: N=768 (6 col tiles), 384 blocks, XCD-swizzled.
template <int MODE>
__global__ __launch_bounds__(256) void gemm_mfma(
    const _Float16* __restrict__ A, const _Float16* __restrict__ Wt,
    const float* __restrict__ bias, float* __restrict__ C,
    const float* __restrict__ attn, const float* __restrict__ gamma)
{
    const int bid = blockIdx.x;
    const int swz = (bid & 7) * 48 + (bid >> 3);
    gemm_body<MODE>(A, Wt, bias, C, 768, swz & 63, swz >> 6, attn, gamma);
}

// Dual GEMM: two independent jobs in one dispatch. Each job count divisible by 8.
__global__ __launch_bounds__(256) void dual_gemm(
    const _Float16* __restrict__ A0, const _Float16* __restrict__ W0,
    const float* __restrict__ b0, float* __restrict__ C0, int ldc0, int cnt0,
    const _Float16* __restrict__ A1, const _Float16* __restrict__ W1,
    const float* __restrict__ b1, float* __restrict__ C1, int ldc1, int cnt1)
{
    int bid = blockIdx.x;
    const _Float16 *A, *Wt; const float* bias; float* C; int ldc, cnt;
    if (bid < cnt0) { A = A0; Wt = W0; bias = b0; C = C0; ldc = ldc0; cnt = cnt0; }
    else { bid -= cnt0; A = A1; Wt = W1; bias = b1; C = C1; ldc = ldc1; cnt = cnt1; }
    const int q = cnt >> 3;
    const int swz = (bid & 7) * q + (bid >> 3);
    gemm_body<0>(A, Wt, bias, C, ldc, swz & 63, swz >> 6, nullptr, nullptr);
}

// ---------------------------------------------------------------------------
// LayerNorm, wave-per-row (4 rows per block, shuffle-only reduce, no LDS).
// Dual-input: rows [0, MTOT) -> X0, [MTOT, 2*MTOT) -> X1.
// ---------------------------------------------------------------------------
__device__ __forceinline__ void ln_wave_body(
    const float* __restrict__ X, _Float16* __restrict__ A,
    const float* __restrict__ g, const float* __restrict__ beta, int row)
{
    const int lane = threadIdx.x & 63;
    const float* x = X + (size_t)row * D_MODEL;
    float v[12];
    float s = 0.f, s2 = 0.f;
#pragma unroll
    for (int j = 0; j < 12; ++j) {
        v[j] = x[lane + 64 * j];
        s += v[j];
        s2 += v[j] * v[j];
    }
#pragma unroll
    for (int m = 1; m < 64; m <<= 1) {
        s += __shfl_xor(s, m);
        s2 += __shfl_xor(s2, m);
    }
    const float mean = s * (1.f / 768.f);
    const float var = s2 * (1.f / 768.f) - mean * mean;
    const float rstd = rsqrtf(var + 1e-6f);
    _Float16* arow = A + (size_t)row * D_MODEL;
#pragma unroll
    for (int j = 0; j < 12; ++j) {
        const int cc = lane + 64 * j;
        arow[cc] = (_Float16)((v[j] - mean) * rstd * g[cc] + beta[cc]);
    }
}

__global__ __launch_bounds__(256) void ln2_wave(
    const float* __restrict__ X0, _Float16* __restrict__ A0,
    const float* __restrict__ g0, const float* __restrict__ b0,
    const float* __restrict__ X1, _Float16* __restrict__ A1,
    const float* __restrict__ g1, const float* __restrict__ b1)
{
    const int r = blockIdx.x * 4 + (threadIdx.x >> 6);
    if (r < MTOT) ln_wave_body(X0, A0, g0, b0, r);
    else          ln_wave_body(X1, A1, g1, b1, r - MTOT);
}

__global__ __launch_bounds__(256) void ln_wave(
    const float* __restrict__ X, _Float16* __restrict__ A,
    const float* __restrict__ g, const float* __restrict__ beta)
{
    const int r = blockIdx.x * 4 + (threadIdx.x >> 6);
    ln_wave_body(X, A, g, beta, r);
}

// ---------------------------------------------------------------------------
// Two fp32 (M x 768) tensors -> fp16 (M x 768)
// ---------------------------------------------------------------------------
__global__ __launch_bounds__(256) void convert_act2(
    const float* __restrict__ X0, _Float16* __restrict__ D0,
    const float* __restrict__ X1, _Float16* __restrict__ D1)
{
    const int i = blockIdx.x * 256 + threadIdx.x;  // over 2*MTOT*192 float4s
    const int sel = i / (MTOT * 192);
    const int r = i - sel * (MTOT * 192);
    const float* X = sel ? X1 : X0;
    _Float16* D = sel ? D1 : D0;
    const int c4 = r * 4;
    const float4 v = *(const float4*)(X + (size_t)c4);
    _Float16 o[4] = {(_Float16)v.x, (_Float16)v.y, (_Float16)v.z, (_Float16)v.w};
    *(uint2*)(D + (size_t)c4) = *(uint2*)o;
}

// ---------------------------------------------------------------------------
// 6 big weights W(768x768 fp32) -> Wt(768x768 fp16, transposed)
// ---------------------------------------------------------------------------
__global__ __launch_bounds__(256) void convert_w6(
    const float* __restrict__ w0, const float* __restrict__ w1,
    const float* __restrict__ w2, const float* __restrict__ w3,
    const float* __restrict__ w4, const float* __restrict__ w5,
    _Float16* __restrict__ Wall)
{
    const int wi = blockIdx.y;
    const float* W = (wi == 0) ? w0 : (wi == 1) ? w1 : (wi == 2) ? w2
                   : (wi == 3) ? w3 : (wi == 4) ? w4 : w5;
    _Float16* Wt = Wall + (size_t)wi * 768 * 768;

    __shared__ float tile[32][33];
    const int tk0 = (blockIdx.x / 24) * 32;
    const int tn0 = (blockIdx.x % 24) * 32;
    const int t = threadIdx.x;
#pragma unroll
    for (int r = 0; r < 4; ++r) {
        const int row = r * 8 + (t >> 5);
        const int col = t & 31;
        tile[row][col] = W[(size_t)(tk0 + row) * 768 + tn0 + col];
    }
    __syncthreads();
    const int n = t >> 3;
    const int kq = (t & 7) * 4;
    _Float16* dst = Wt + (size_t)(tn0 + n) * 768 + tk0 + kq;
#pragma unroll
    for (int u = 0; u < 4; ++u) dst[u] = (_Float16)tile[kq + u][n];
}

// ---------------------------------------------------------------------------
// Combined offset|aw weights -> Wt(256 x 768 fp16, transposed), rows 192..255
// zero; combined bias (256). Two pairs (cross, self).
// ---------------------------------------------------------------------------
__global__ __launch_bounds__(256) void convert_offa(
    const float* __restrict__ Woff_c, const float* __restrict__ Wa_c,
    const float* __restrict__ boff_c, const float* __restrict__ ba_c,
    const float* __restrict__ Woff_s, const float* __restrict__ Wa_s,
    const float* __restrict__ boff_s, const float* __restrict__ ba_s,
    _Float16* __restrict__ Wc, _Float16* __restrict__ Ws,
    float* __restrict__ bias_c, float* __restrict__ bias_s)
{
    const int i = blockIdx.x * 256 + threadIdx.x;  // 2*256*192
    if (i >= 2 * 256 * 192) return;
    const int pair = i / (256 * 192);
    const int r = i - pair * (256 * 192);
    const int n = r / 192;
    const int k0 = (r - n * 192) * 4;
    const float* Woff = pair ? Woff_s : Woff_c;
    const float* Wa = pair ? Wa_s : Wa_c;
    _Float16* dst = pair ? Ws : Wc;
    _Float16* row = dst + (size_t)n * 768;
#pragma unroll
    for (int u = 0; u < 4; ++u) {
        const int k = k0 + u;
        float v = (n < 128) ? Woff[(size_t)k * 128 + n]
                : (n < 192) ? Wa[(size_t)k * 64 + (n - 128)] : 0.f;
        row[k] = (_Float16)v;
    }
    if (k0 == 0) {
        const float* boff = pair ? boff_s : boff_c;
        const float* ba = pair ? ba_s : ba_c;
        float* bias = pair ? bias_s : bias_c;
        bias[n] = (n < 128) ? boff[n] : (n < 192) ? ba[n - 128] : 0.f;
    }
}

// ---------------------------------------------------------------------------
// softmax over P=4 + sampling loc. Reads combined (M x 256): off at 0, aw at 128.
// ---------------------------------------------------------------------------
__global__ __launch_bounds__(256) void offaw_post(
    const float* __restrict__ offc,
    float* __restrict__ loc, float* __restrict__ aw)
{
    const int i = blockIdx.x * 256 + threadIdx.x;
    if (i >= MTOT * NH) return;
    const int h = i & (NH - 1);
    const int bq = i >> 4;
    const int q = bq & (LQ - 1);

    const float* orow = offc + (size_t)bq * 256 + h * 8;
    const float* arow = offc + (size_t)bq * 256 + 128 + h * 4;

    float a0 = arow[0], a1 = arow[1], a2 = arow[2], a3 = arow[3];
    float mx = fmaxf(fmaxf(a0, a1), fmaxf(a2, a3));
    float e0 = expf(a0 - mx), e1 = expf(a1 - mx), e2 = expf(a2 - mx), e3 = expf(a3 - mx);
    float r = 1.f / (e0 + e1 + e2 + e3);

    const float refx = ((q & 63) + 0.5f) * (1.f / 64.f);
    const float refy = ((q >> 6) + 0.5f) * (1.f / 64.f);
#pragma unroll
    for (int p = 0; p < 4; ++p) {
        loc[(size_t)i * 8 + p * 2 + 0] = refx + orow[p * 2 + 0] * (1.f / 64.f);
        loc[(size_t)i * 8 + p * 2 + 1] = refy + orow[p * 2 + 1] * (1.f / 64.f);
    }
    aw[(size_t)i * 4 + 0] = e0 * r;
    aw[(size_t)i * 4 + 1] = e1 * r;
    aw[(size_t)i * 4 + 2] = e2 * r;
    aw[(size_t)i * 4 + 3] = e3 * r;
}

// ---------------------------------------------------------------------------
// Bilinear sampling, float4 over d, fp16 output (GEMM A operand).
// XCD-chunk swizzle: consecutive q-span per XCD -> sampled value region (~4 MB)
// fits the per-XCD 4 MB L2 (offsets bounded ~±3 cells).
// Thread -> (bqh, c) with c in [0,12): d = 4c..4c+3.
// ---------------------------------------------------------------------------
__global__ __launch_bounds__(256) void sample_f4(
    const float* __restrict__ value, const float* __restrict__ loc,
    const float* __restrict__ aw, _Float16* __restrict__ A)
{
    const int bid = blockIdx.x;                       // 6144 = 8 * 768
    const int swz = (bid & 7) * 768 + (bid >> 3);     // XCD-chunk swizzle
    const int idx = swz * 256 + threadIdx.x;          // MTOT*NH*12
    const int bqh = idx / 12;
    const int c = idx - bqh * 12;
    const int d0 = c * 4;
    const int h = bqh & (NH - 1);
    const int bq = bqh >> 4;
    const int b = bq >> 12;

    const float4 l01 = *(const float4*)(loc + (size_t)bqh * 8);
    const float4 l23 = *(const float4*)(loc + (size_t)bqh * 8 + 4);
    const float4 w4 = *(const float4*)(aw + (size_t)bqh * 4);
    const float lx[4] = {l01.x, l01.z, l23.x, l23.z};
    const float ly[4] = {l01.y, l01.w, l23.y, l23.w};
    const float wp4[4] = {w4.x, w4.y, w4.z, w4.w};

    const float* vbase = value + (size_t)b * LQ * D_MODEL + h * DH + d0;

    float4 acc = {0.f, 0.f, 0.f, 0.f};
#pragma unroll
    for (int p = 0; p < 4; ++p) {
        const float x = lx[p] * 64.f - 0.5f;
        const float y = ly[p] * 64.f - 0.5f;
        const float xf = floorf(x), yf = floorf(y);
        const float wx1 = x - xf, wy1 = y - yf;
        const float wx0 = 1.f - wx1, wy0 = 1.f - wy1;
        const int x0 = (int)xf, y0 = (int)yf;
        const int x1 = x0 + 1, y1 = y0 + 1;
        const float wp = wp4[p];
        const bool vx0 = (x0 >= 0) && (x0 < 64);
        const bool vx1 = (x1 >= 0) && (x1 < 64);
        const bool vy0 = (y0 >= 0) && (y0 < 64);
        const bool vy1 = (y1 >= 0) && (y1 < 64);
        const float cw[4] = {wp * wx0 * wy0, wp * wx1 * wy0, wp * wx0 * wy1, wp * wx1 * wy1};
        const bool cv[4] = {vx0 && vy0, vx1 && vy0, vx0 && vy1, vx1 && vy1};
        const int cxy[4][2] = {{x0, y0}, {x1, y0}, {x0, y1}, {x1, y1}};
#pragma unroll
        for (int k = 0; k < 4; ++k) {
            if (cv[k]) {
                const float4 g = *(const float4*)(vbase + (size_t)(cxy[k][1] * 64 + cxy[k][0]) * D_MODEL);
                acc.x += cw[k] * g.x; acc.y += cw[k] * g.y;
                acc.z += cw[k] * g.z; acc.w += cw[k] * g.w;
            }
        }
    }

    _Float16* arow = A + (size_t)bq * D_MODEL + h * DH + d0;
    _Float16 o[4] = {(_Float16)acc.x, (_Float16)acc.y, (_Float16)acc.z, (_Float16)acc.w};
    *(uint2*)arow = *(uint2*)o;
}

// ---------------------------------------------------------------------------
extern "C" void kernel_launch(void* const* d_in, const int* in_sizes, int n_in,
                              void* d_out, int out_size, void* d_ws, size_t ws_size,
                              hipStream_t stream)
{
    const float* query   = (const float*)d_in[0];
    const float* feat    = (const float*)d_in[1];
    const float* qn_W    = (const float*)d_in[4];
    const float* qn_b    = (const float*)d_in[5];
    const float* qn_g    = (const float*)d_in[6];
    const float* qn_beta = (const float*)d_in[7];
    const float* fn_W    = (const float*)d_in[8];
    const float* fn_b    = (const float*)d_in[9];
    const float* fn_g    = (const float*)d_in[10];
    const float* fn_beta = (const float*)d_in[11];
    const float* nm_g    = (const float*)d_in[12];
    const float* nm_beta = (const float*)d_in[13];
    const float* gamma1  = (const float*)d_in[14];
    const float* c_Wv    = (const float*)d_in[15];
    const float* c_bv    = (const float*)d_in[16];
    const float* c_Woff  = (const float*)d_in[17];
    const float* c_boff  = (const float*)d_in[18];
    const float* c_Wa    = (const float*)d_in[19];
    const float* c_ba    = (const float*)d_in[20];
    const float* c_Wo    = (const float*)d_in[21];
    const float* c_bo    = (const float*)d_in[22];
    const float* s_Wv    = (const float*)d_in[23];
    const float* s_bv    = (const float*)d_in[24];
    const float* s_Woff  = (const float*)d_in[25];
    const float* s_boff  = (const float*)d_in[26];
    const float* s_Wa    = (const float*)d_in[27];
    const float* s_ba    = (const float*)d_in[28];
    const float* s_Wo    = (const float*)d_in[29];
    const float* s_bo    = (const float*)d_in[30];

    float* ws = (float*)d_ws;
    const size_t SZ = (size_t)MTOT * D_MODEL;  // 6291456 floats
    float* buf0 = ws;            // qn pre-LN fp32; later offc (M x 256)
    float* buf1 = ws + SZ;       // fn pre-LN fp32
    float* buf2 = ws + 2 * SZ;   // val fp32
    float* buf3 = ws + 3 * SZ;   // attn fp32 (live to the end)
    _Float16* slotA = (_Float16*)(ws + 4 * SZ);           // query-raw -> qn -> attn1 (M x 768 fp16)
    _Float16* slotB = (_Float16*)(ws + 4 * SZ + SZ / 2);  // feat-raw -> fn -> samp
    float* loc    = ws + 5 * SZ;                    // MTOT*128
    float* aws    = loc + (size_t)MTOT * 128;       // MTOT*64
    float* bias_c = aws + (size_t)MTOT * 64;        // 256
    float* bias_s = bias_c + 256;                   // 256
    _Float16* W6 = (_Float16*)(bias_s + 256);       // 6 x 768 x 768 fp16
    _Float16* W_qn  = W6 + (size_t)0 * 768 * 768;
    _Float16* W_fn  = W6 + (size_t)1 * 768 * 768;
    _Float16* W_cWv = W6 + (size_t)2 * 768 * 768;
    _Float16* W_cWo = W6 + (size_t)3 * 768 * 768;
    _Float16* W_sWv = W6 + (size_t)4 * 768 * 768;
    _Float16* W_sWo = W6 + (size_t)5 * 768 * 768;
    _Float16* Woffa_c = W6 + (size_t)6 * 768 * 768;       // 256 x 768
    _Float16* Woffa_s = Woffa_c + (size_t)256 * 768;

    float* out = (float*)d_out;
    const dim3 blk(256);

    // ---- weight + activation conversion ----
    convert_w6<<<dim3(576, 6), blk, 0, stream>>>(qn_W, fn_W, c_Wv, c_Wo, s_Wv, s_Wo, W6);
    convert_offa<<<384, blk, 0, stream>>>(c_Woff, c_Wa, c_boff, c_ba,
                                          s_Woff, s_Wa, s_boff, s_ba,
                                          Woffa_c, Woffa_s, bias_c, bias_s);
    convert_act2<<<12288, blk, 0, stream>>>(query, slotA, feat, slotB);

    // ---- cross attention ----
    // G1: qn = query@qn_W + b ; fn = feat@fn_W + b
    dual_gemm<<<768, blk, 0, stream>>>(slotA, W_qn, qn_b, buf0, 768, 384,
                                       slotB, W_fn, fn_b, buf1, 768, 384);
    ln2_wave<<<2 * MTOT / 4, blk, 0, stream>>>(buf0, slotA, qn_g, qn_beta,
                                               buf1, slotB, fn_g, fn_beta);
    // G2: val = fn@c_Wv ; offc = qn@[c_Woff|c_Wa]
    dual_gemm<<<512, blk, 0, stream>>>(slotB, W_cWv, c_bv, buf2, 768, 384,
                                       slotA, Woffa_c, bias_c, buf0, 256, 128);
    offaw_post<<<(MTOT * NH + 255) / 256, blk, 0, stream>>>(buf0, loc, aws);
    sample_f4<<<MTOT * NH * 12 / 256, blk, 0, stream>>>(buf2, loc, aws, slotB);
    gemm_mfma<0><<<384, blk, 0, stream>>>(slotB, W_cWo, c_bo, buf3, nullptr, nullptr);

    // ---- self attention ----
    ln_wave<<<MTOT / 4, blk, 0, stream>>>(buf3, slotA, nm_g, nm_beta);  // attn1 -> slotA
    // G4: val = attn1@s_Wv ; offc = attn1@[s_Woff|s_Wa]
    dual_gemm<<<512, blk, 0, stream>>>(slotA, W_sWv, s_bv, buf2, 768, 384,
                                       slotA, Woffa_s, bias_s, buf0, 256, 128);
    offaw_post<<<(MTOT * NH + 255) / 256, blk, 0, stream>>>(buf0, loc, aws);
    sample_f4<<<MTOT * NH * 12 / 256, blk, 0, stream>>>(buf2, loc, aws, slotB);
    // final: out = gamma1 * (attn + samp@s_Wo + s_bo)
    gemm_mfma<1><<<384, blk, 0, stream>>>(slotB, W_sWo, s_bo, out, buf3, gamma1);
}

// Round 7
// 354.758 us; speedup vs baseline: 4.2551x; 1.0780x over previous
//
#include <hip/hip_runtime.h>
#include <hip/hip_bf16.h>
#include <math.h>

#define D_MODEL 768
#define NH 16
#define DH 48
#define NP 4
#define LQ 4096
#define BB 2
#define MTOT (BB * LQ)  // 8192

typedef __attribute__((ext_vector_type(8))) _Float16 half8_t;
typedef __attribute__((ext_vector_type(4))) float floatx4;

__device__ __forceinline__ void load_lds16(const void* g, void* l) {
    __builtin_amdgcn_global_load_lds((const __attribute__((address_space(1))) void*)g,
                                     (__attribute__((address_space(3))) void*)l, 16, 0, 0);
}

// ---------------------------------------------------------------------------
// fp16 MFMA GEMM tile body, 2-phase double-buffered: STAGE(next) issued BEFORE
// compute(cur); ONE barrier per K-step. A: (M x 768 fp16); Wt: (ldc x 768 fp16,
// transposed). 128x128 tile, BK=32, 4 waves (2x2), 4x4 16x16x32 MFMA per wave.
// MODE 0: fp32 C = acc + bias
// MODE 1: fp32 C = gamma[col]*(attn[row,col] + acc + bias)
// MODE 2: fp16 C = acc + bias   (value tensor output)
// ---------------------------------------------------------------------------
template <int MODE>
__device__ __forceinline__ void gemm_body(
    const _Float16* __restrict__ A, const _Float16* __restrict__ Wt,
    const float* __restrict__ bias, void* __restrict__ Cv, int ldc,
    int tm, int tn,
    const float* __restrict__ attn, const float* __restrict__ gamma)
{
    constexpr int K = 768;
    constexpr int NT = K / 32;  // 24 K-steps
    __shared__ _Float16 As[2][128 * 32];
    __shared__ _Float16 Bs[2][128 * 32];

    const int bm = tm * 128, bn = tn * 128;
    const int t = threadIdx.x;
    const int lane = t & 63;
    const int w = t >> 6;
    const int wm = (w >> 1) * 64, wn = (w & 1) * 64;

    floatx4 acc[4][4] = {};

    const int r0 = t >> 2;
    const int c8 = (t & 3) * 8;
    const size_t arow0 = (size_t)(bm + r0) * K + c8;
    const size_t arow1 = (size_t)(bm + 64 + r0) * K + c8;
    const size_t brow0 = (size_t)(bn + r0) * K + c8;
    const size_t brow1 = (size_t)(bn + 64 + r0) * K + c8;

    const int lrow = lane & 15;
    const int lk = (lane >> 4) * 8;

    load_lds16(A + arow0, &As[0][w * 512]);
    load_lds16(A + arow1, &As[0][2048 + w * 512]);
    load_lds16(Wt + brow0, &Bs[0][w * 512]);
    load_lds16(Wt + brow1, &Bs[0][2048 + w * 512]);
    __syncthreads();

    for (int ti = 0; ti < NT; ++ti) {
        const int cur = ti & 1;
        if (ti + 1 < NT) {
            const int kn = (ti + 1) * 32;
            const int nxt = cur ^ 1;
            load_lds16(A + arow0 + kn, &As[nxt][w * 512]);
            load_lds16(A + arow1 + kn, &As[nxt][2048 + w * 512]);
            load_lds16(Wt + brow0 + kn, &Bs[nxt][w * 512]);
            load_lds16(Wt + brow1 + kn, &Bs[nxt][2048 + w * 512]);
        }

        const _Float16* Ac = As[cur];
        const _Float16* Bc = Bs[cur];
        half8_t af[4], bf[4];
#pragma unroll
        for (int i = 0; i < 4; ++i) {
            af[i] = *(const half8_t*)&Ac[(wm + i * 16 + lrow) * 32 + lk];
            bf[i] = *(const half8_t*)&Bc[(wn + i * 16 + lrow) * 32 + lk];
        }
#pragma unroll
        for (int i = 0; i < 4; ++i)
#pragma unroll
            for (int j = 0; j < 4; ++j)
                acc[i][j] = __builtin_amdgcn_mfma_f32_16x16x32_f16(af[i], bf[j], acc[i][j], 0, 0, 0);

        if (ti + 1 < NT) __syncthreads();
    }

    // epilogue: C/D layout col=lane&15, row=(lane>>4)*4+reg
    const int rquad = (lane >> 4) * 4;
#pragma unroll
    for (int i = 0; i < 4; ++i) {
#pragma unroll
        for (int j = 0; j < 4; ++j) {
            const int col = bn + wn + j * 16 + lrow;
            const float bcol = bias[col];
#pragma unroll
            for (int r = 0; r < 4; ++r) {
                const size_t row = (size_t)(bm + wm + i * 16 + rquad + r);
                float v = acc[i][j][r] + bcol;
                if (MODE == 1) v = (attn[row * ldc + col] + v) * gamma[col];
                if (MODE == 2) ((_Float16*)Cv)[row * (size_t)ldc + col] = (_Float16)v;
                else           ((float*)Cv)[row * (size_t)ldc + col] = v;
            }
        }
    }
}

// Single GEMM: N=768 (6 col tiles), 384 blocks, XCD-swizzled.
template <int MODE>
__global__ __launch_bounds__(256) void gemm_mfma(
    const _Float16* __restrict__ A, const _Float16* __restrict__ Wt,
    const float* __restrict__ bias, void* __restrict__ C,
    const float* __restrict__ attn, const float* __restrict__ gamma)
{
    const int bid = blockIdx.x;
    const int swz = (bid & 7) * 48 + (bid >> 3);
    gemm_body<MODE>(A, Wt, bias, C, 768, swz & 63, swz >> 6, attn, gamma);
}

// Dual GEMM: two independent jobs, per-job output mode. Counts divisible by 8.
template <int M0, int M1>
__global__ __launch_bounds__(256) void dual_gemm(
    const _Float16* __restrict__ A0, const _Float16* __restrict__ W0,
    const float* __restrict__ b0, void* __restrict__ C0, int ldc0, int cnt0,
    const _Float16* __restrict__ A1, const _Float16* __restrict__ W1,
    const float* __restrict__ b1, void* __restrict__ C1, int ldc1, int cnt1)
{
    int bid = blockIdx.x;
    if (bid < cnt0) {
        const int q = cnt0 >> 3;
        const int swz = (bid & 7) * q + (bid >> 3);
        gemm_body<M0>(A0, W0, b0, C0, ldc0, swz & 63, swz >> 6, nullptr, nullptr);
    } else {
        bid -= cnt0;
        const int q = cnt1 >> 3;
        const int swz = (bid & 7) * q + (bid >> 3);
        gemm_body<M1>(A1, W1, b1, C1, ldc1, swz & 63, swz >> 6, nullptr, nullptr);
    }
}

// ---------------------------------------------------------------------------
// LayerNorm, wave-per-row (4 rows per block, shuffle-only reduce, no LDS).
// ---------------------------------------------------------------------------
__device__ __forceinline__ void ln_wave_body(
    const float* __restrict__ X, _Float16* __restrict__ A,
    const float* __restrict__ g, const float* __restrict__ beta, int row)
{
    const int lane = threadIdx.x & 63;
    const float* x = X + (size_t)row * D_MODEL;
    float v[12];
    float s = 0.f, s2 = 0.f;
#pragma unroll
    for (int j = 0; j < 12; ++j) {
        v[j] = x[lane + 64 * j];
        s += v[j];
        s2 += v[j] * v[j];
    }
#pragma unroll
    for (int m = 1; m < 64; m <<= 1) {
        s += __shfl_xor(s, m);
        s2 += __shfl_xor(s2, m);
    }
    const float mean = s * (1.f / 768.f);
    const float var = s2 * (1.f / 768.f) - mean * mean;
    const float rstd = rsqrtf(var + 1e-6f);
    _Float16* arow = A + (size_t)row * D_MODEL;
#pragma unroll
    for (int j = 0; j < 12; ++j) {
        const int cc = lane + 64 * j;
        arow[cc] = (_Float16)((v[j] - mean) * rstd * g[cc] + beta[cc]);
    }
}

__global__ __launch_bounds__(256) void ln2_wave(
    const float* __restrict__ X0, _Float16* __restrict__ A0,
    const float* __restrict__ g0, const float* __restrict__ b0,
    const float* __restrict__ X1, _Float16* __restrict__ A1,
    const float* __restrict__ g1, const float* __restrict__ b1)
{
    const int r = blockIdx.x * 4 + (threadIdx.x >> 6);
    if (r < MTOT) ln_wave_body(X0, A0, g0, b0, r);
    else          ln_wave_body(X1, A1, g1, b1, r - MTOT);
}

__global__ __launch_bounds__(256) void ln_wave(
    const float* __restrict__ X, _Float16* __restrict__ A,
    const float* __restrict__ g, const float* __restrict__ beta)
{
    const int r = blockIdx.x * 4 + (threadIdx.x >> 6);
    ln_wave_body(X, A, g, beta, r);
}

// ---------------------------------------------------------------------------
// Merged conversions: [0,12288) act fp32->fp16; [12288,15744) weight transpose
// fp32->fp16; [15744,16128) combined offset|aw weights + bias.
// ---------------------------------------------------------------------------
__global__ __launch_bounds__(256) void convert_all(
    const float* __restrict__ query, _Float16* __restrict__ actA,
    const float* __restrict__ feat, _Float16* __restrict__ actB,
    const float* __restrict__ w0, const float* __restrict__ w1,
    const float* __restrict__ w2, const float* __restrict__ w3,
    const float* __restrict__ w4, const float* __restrict__ w5,
    _Float16* __restrict__ Wall,
    const float* __restrict__ Woff_c, const float* __restrict__ Wa_c,
    const float* __restrict__ boff_c, const float* __restrict__ ba_c,
    const float* __restrict__ Woff_s, const float* __restrict__ Wa_s,
    const float* __restrict__ boff_s, const float* __restrict__ ba_s,
    _Float16* __restrict__ Wc, _Float16* __restrict__ Ws,
    float* __restrict__ bias_c, float* __restrict__ bias_s)
{
    __shared__ float tile[32][33];
    const int bid = blockIdx.x;
    const int t = threadIdx.x;

    if (bid < 12288) {
        // activations: 2*MTOT*192 float4s
        const int i = bid * 256 + t;
        const int sel = i / (MTOT * 192);
        const int r = i - sel * (MTOT * 192);
        const float* X = sel ? feat : query;
        _Float16* D = sel ? actB : actA;
        const int c4 = r * 4;
        const float4 v = *(const float4*)(X + (size_t)c4);
        _Float16 o[4] = {(_Float16)v.x, (_Float16)v.y, (_Float16)v.z, (_Float16)v.w};
        *(uint2*)(D + (size_t)c4) = *(uint2*)o;
    } else if (bid < 15744) {
        const int g = bid - 12288;           // 0..3455
        const int wi = g / 576;
        const int gx = g - wi * 576;
        const float* W = (wi == 0) ? w0 : (wi == 1) ? w1 : (wi == 2) ? w2
                       : (wi == 3) ? w3 : (wi == 4) ? w4 : w5;
        _Float16* Wt = Wall + (size_t)wi * 768 * 768;
        const int tk0 = (gx / 24) * 32;
        const int tn0 = (gx % 24) * 32;
#pragma unroll
        for (int r = 0; r < 4; ++r) {
            const int row = r * 8 + (t >> 5);
            const int col = t & 31;
            tile[row][col] = W[(size_t)(tk0 + row) * 768 + tn0 + col];
        }
        __syncthreads();
        const int n = t >> 3;
        const int kq = (t & 7) * 4;
        _Float16* dst = Wt + (size_t)(tn0 + n) * 768 + tk0 + kq;
#pragma unroll
        for (int u = 0; u < 4; ++u) dst[u] = (_Float16)tile[kq + u][n];
    } else {
        const int i = (bid - 15744) * 256 + t;  // 2*256*192
        if (i >= 2 * 256 * 192) return;
        const int pair = i / (256 * 192);
        const int r = i - pair * (256 * 192);
        const int n = r / 192;
        const int k0 = (r - n * 192) * 4;
        const float* Woff = pair ? Woff_s : Woff_c;
        const float* Wa = pair ? Wa_s : Wa_c;
        _Float16* dst = pair ? Ws : Wc;
        _Float16* row = dst + (size_t)n * 768;
#pragma unroll
        for (int u = 0; u < 4; ++u) {
            const int k = k0 + u;
            float v = (n < 128) ? Woff[(size_t)k * 128 + n]
                    : (n < 192) ? Wa[(size_t)k * 64 + (n - 128)] : 0.f;
            row[k] = (_Float16)v;
        }
        if (k0 == 0) {
            const float* boff = pair ? boff_s : boff_c;
            const float* ba = pair ? ba_s : ba_c;
            float* bias = pair ? bias_s : bias_c;
            bias[n] = (n < 128) ? boff[n] : (n < 192) ? ba[n - 128] : 0.f;
        }
    }
}

// ---------------------------------------------------------------------------
// Fused softmax/loc + bilinear sampling. 192-thread blocks, each covers 2 bq.
// Threads 0..31 compute loc/aw for the block's 32 (bq,h) into LDS; then all
// 192 threads sample: thread -> (lbqh = tid/6, c = tid%6), d0 = 8c, fp16 val.
// XCD-chunk swizzle over 4096 blocks.
// ---------------------------------------------------------------------------
__global__ __launch_bounds__(192) void sample_fused(
    const _Float16* __restrict__ value, const float* __restrict__ offc,
    _Float16* __restrict__ A)
{
    __shared__ float loc_s[32][8];
    __shared__ float aw_s[32][4];

    const int bid = blockIdx.x;                    // 4096 = 8 * 512
    const int swz = (bid & 7) * 512 + (bid >> 3);  // XCD-chunk swizzle
    const int bq_base = swz * 2;
    const int t = threadIdx.x;

    if (t < 32) {
        const int bq = bq_base + (t >> 4);
        const int h = t & 15;
        const int q = bq & (LQ - 1);
        const float* orow = offc + (size_t)bq * 256 + h * 8;
        const float* arow = offc + (size_t)bq * 256 + 128 + h * 4;
        float a0 = arow[0], a1 = arow[1], a2 = arow[2], a3 = arow[3];
        float mx = fmaxf(fmaxf(a0, a1), fmaxf(a2, a3));
        float e0 = expf(a0 - mx), e1 = expf(a1 - mx), e2 = expf(a2 - mx), e3 = expf(a3 - mx);
        float r = 1.f / (e0 + e1 + e2 + e3);
        const float refx = ((q & 63) + 0.5f) * (1.f / 64.f);
        const float refy = ((q >> 6) + 0.5f) * (1.f / 64.f);
#pragma unroll
        for (int p = 0; p < 4; ++p) {
            loc_s[t][p * 2 + 0] = refx + orow[p * 2 + 0] * (1.f / 64.f);
            loc_s[t][p * 2 + 1] = refy + orow[p * 2 + 1] * (1.f / 64.f);
        }
        aw_s[t][0] = e0 * r; aw_s[t][1] = e1 * r;
        aw_s[t][2] = e2 * r; aw_s[t][3] = e3 * r;
    }
    __syncthreads();

    const int lbqh = t / 6;
    const int c = t - lbqh * 6;
    const int d0 = c * 8;
    const int bq = bq_base + (lbqh >> 4);
    const int h = lbqh & 15;
    const int b = bq >> 12;

    const _Float16* vbase = value + (size_t)b * LQ * D_MODEL + h * DH + d0;

    float acc[8] = {};
#pragma unroll
    for (int p = 0; p < 4; ++p) {
        const float x = loc_s[lbqh][p * 2 + 0] * 64.f - 0.5f;
        const float y = loc_s[lbqh][p * 2 + 1] * 64.f - 0.5f;
        const float xf = floorf(x), yf = floorf(y);
        const float wx1 = x - xf, wy1 = y - yf;
        const float wx0 = 1.f - wx1, wy0 = 1.f - wy1;
        const int x0 = (int)xf, y0 = (int)yf;
        const int x1 = x0 + 1, y1 = y0 + 1;
        const float wp = aw_s[lbqh][p];
        const bool vx0 = (x0 >= 0) && (x0 < 64);
        const bool vx1 = (x1 >= 0) && (x1 < 64);
        const bool vy0 = (y0 >= 0) && (y0 < 64);
        const bool vy1 = (y1 >= 0) && (y1 < 64);
        const float cw[4] = {wp * wx0 * wy0, wp * wx1 * wy0, wp * wx0 * wy1, wp * wx1 * wy1};
        const bool cv[4] = {vx0 && vy0, vx1 && vy0, vx0 && vy1, vx1 && vy1};
        const int cxy[4][2] = {{x0, y0}, {x1, y0}, {x0, y1}, {x1, y1}};
#pragma unroll
        for (int k = 0; k < 4; ++k) {
            if (cv[k]) {
                const half8_t g = *(const half8_t*)(vbase + (size_t)(cxy[k][1] * 64 + cxy[k][0]) * D_MODEL);
#pragma unroll
                for (int u = 0; u < 8; ++u) acc[u] += cw[k] * (float)g[u];
            }
        }
    }

    _Float16* arow = A + (size_t)bq * D_MODEL + h * DH + d0;
    _Float16 o[8];
#pragma unroll
    for (int u = 0; u < 8; ++u) o[u] = (_Float16)acc[u];
    *(uint4*)arow = *(uint4*)o;
}

// ---------------------------------------------------------------------------
extern "C" void kernel_launch(void* const* d_in, const int* in_sizes, int n_in,
                              void* d_out, int out_size, void* d_ws, size_t ws_size,
                              hipStream_t stream)
{
    const float* query   = (const float*)d_in[0];
    const float* feat    = (const float*)d_in[1];
    const float* qn_W    = (const float*)d_in[4];
    const float* qn_b    = (const float*)d_in[5];
    const float* qn_g    = (const float*)d_in[6];
    const float* qn_beta = (const float*)d_in[7];
    const float* fn_W    = (const float*)d_in[8];
    const float* fn_b    = (const float*)d_in[9];
    const float* fn_g    = (const float*)d_in[10];
    const float* fn_beta = (const float*)d_in[11];
    const float* nm_g    = (const float*)d_in[12];
    const float* nm_beta = (const float*)d_in[13];
    const float* gamma1  = (const float*)d_in[14];
    const float* c_Wv    = (const float*)d_in[15];
    const float* c_bv    = (const float*)d_in[16];
    const float* c_Woff  = (const float*)d_in[17];
    const float* c_boff  = (const float*)d_in[18];
    const float* c_Wa    = (const float*)d_in[19];
    const float* c_ba    = (const float*)d_in[20];
    const float* c_Wo    = (const float*)d_in[21];
    const float* c_bo    = (const float*)d_in[22];
    const float* s_Wv    = (const float*)d_in[23];
    const float* s_bv    = (const float*)d_in[24];
    const float* s_Woff  = (const float*)d_in[25];
    const float* s_boff  = (const float*)d_in[26];
    const float* s_Wa    = (const float*)d_in[27];
    const float* s_ba    = (const float*)d_in[28];
    const float* s_Wo    = (const float*)d_in[29];
    const float* s_bo    = (const float*)d_in[30];

    float* ws = (float*)d_ws;
    const size_t SZ = (size_t)MTOT * D_MODEL;  // 6291456 floats
    float* buf0 = ws;                          // qn pre-LN fp32; later offc (M x 256)
    float* buf1 = ws + SZ;                     // fn pre-LN fp32
    _Float16* val16 = (_Float16*)(ws + 2 * SZ);   // value tensor fp16 (M x 768)
    float* buf3 = ws + 3 * SZ;                 // attn fp32 (live to the end)
    _Float16* slotA = (_Float16*)(ws + 4 * SZ);           // query -> qn -> attn1 fp16
    _Float16* slotB = (_Float16*)(ws + 4 * SZ + SZ / 2);  // feat -> fn -> samp fp16
    float* bias_c = ws + 5 * SZ;               // 256
    float* bias_s = bias_c + 256;              // 256
    _Float16* W6 = (_Float16*)(bias_s + 256);  // 6 x 768 x 768 fp16
    _Float16* W_qn  = W6 + (size_t)0 * 768 * 768;
    _Float16* W_fn  = W6 + (size_t)1 * 768 * 768;
    _Float16* W_cWv = W6 + (size_t)2 * 768 * 768;
    _Float16* W_cWo = W6 + (size_t)3 * 768 * 768;
    _Float16* W_sWv = W6 + (size_t)4 * 768 * 768;
    _Float16* W_sWo = W6 + (size_t)5 * 768 * 768;
    _Float16* Woffa_c = W6 + (size_t)6 * 768 * 768;       // 256 x 768
    _Float16* Woffa_s = Woffa_c + (size_t)256 * 768;
    float* offc = buf0;

    float* out = (float*)d_out;
    const dim3 blk(256);

    // ---- all conversions in one dispatch ----
    convert_all<<<16128, blk, 0, stream>>>(
        query, slotA, feat, slotB,
        qn_W, fn_W, c_Wv, c_Wo, s_Wv, s_Wo, W6,
        c_Woff, c_Wa, c_boff, c_ba, s_Woff, s_Wa, s_boff, s_ba,
        Woffa_c, Woffa_s, bias_c, bias_s);

    // ---- cross attention ----
    dual_gemm<0, 0><<<768, blk, 0, stream>>>(slotA, W_qn, qn_b, buf0, 768, 384,
                                             slotB, W_fn, fn_b, buf1, 768, 384);
    ln2_wave<<<2 * MTOT / 4, blk, 0, stream>>>(buf0, slotA, qn_g, qn_beta,
                                               buf1, slotB, fn_g, fn_beta);
    dual_gemm<2, 0><<<512, blk, 0, stream>>>(slotB, W_cWv, c_bv, val16, 768, 384,
                                             slotA, Woffa_c, bias_c, offc, 256, 128);
    sample_fused<<<4096, dim3(192), 0, stream>>>(val16, offc, slotB);
    gemm_mfma<0><<<384, blk, 0, stream>>>(slotB, W_cWo, c_bo, buf3, nullptr, nullptr);

    // ---- self attention ----
    ln_wave<<<MTOT / 4, blk, 0, stream>>>(buf3, slotA, nm_g, nm_beta);
    dual_gemm<2, 0><<<512, blk, 0, stream>>>(slotA, W_sWv, s_bv, val16, 768, 384,
                                             slotA, Woffa_s, bias_s, offc, 256, 128);
    sample_fused<<<4096, dim3(192), 0, stream>>>(val16, offc, slotB);
    gemm_mfma<1><<<384, blk, 0, stream>>>(slotB, W_sWo, s_bo, out, buf3, gamma1);
}